// Round 10
// baseline (372.221 us; speedup 1.0000x reference)
//
#include <hip/hip_runtime.h>
#include <cstdint>

typedef __bf16 bf16;
typedef __bf16 bf16x8 __attribute__((ext_vector_type(8)));
typedef float f32x4 __attribute__((ext_vector_type(4)));

#define DEVI __device__ __forceinline__

DEVI float bits2f(uint32_t u){ union{uint32_t u;float f;}x; x.u=u; return x.f; }

DEVI void gload_lds16(const void* g, void* l){
  __builtin_amdgcn_global_load_lds(
    (const __attribute__((address_space(1))) uint32_t*)g,
    (__attribute__((address_space(3))) uint32_t*)l, 16, 0, 0);
}

// ---------- cast fp32 -> bf16, 8 elems/thread ----------
__global__ __launch_bounds__(256) void k_cast(const float* __restrict__ x, bf16* __restrict__ o, int n){
  int i = (blockIdx.x*256 + threadIdx.x)*8;
  if (i >= n) return;
  float4 a = *(const float4*)(x+i);
  float4 b = *(const float4*)(x+i+4);
  union { bf16 h[8]; uint4 u; } r;
  r.h[0]=(bf16)a.x; r.h[1]=(bf16)a.y; r.h[2]=(bf16)a.z; r.h[3]=(bf16)a.w;
  r.h[4]=(bf16)b.x; r.h[5]=(bf16)b.y; r.h[6]=(bf16)b.z; r.h[7]=(bf16)b.w;
  *(uint4*)(o+i) = r.u;
}

// ---------- fused: read x fp32 once -> xb (bf16) + xT (bf16 transposed) ----------
__global__ __launch_bounds__(256) void k_castT(const float* __restrict__ x, bf16* __restrict__ xb,
                                               bf16* __restrict__ xT){
  const int b = blockIdx.z;
  x  += (size_t)b*4194304; xb += (size_t)b*4194304; xT += (size_t)b*4194304;
  const int n0 = blockIdx.y*64, c0 = blockIdx.x*64;
  __shared__ float sF[64][65];
  const int t = threadIdx.x;
  const int lr = t>>4, lc4 = (t&15)*4;
  #pragma unroll
  for (int i=0;i<4;++i){
    int r = lr + i*16;
    float4 v = *(const float4*)(x + (size_t)(n0+r)*1024 + c0 + lc4);
    sF[r][lc4+0]=v.x; sF[r][lc4+1]=v.y; sF[r][lc4+2]=v.z; sF[r][lc4+3]=v.w;
  }
  __syncthreads();
  const int wr = t>>3, wc8 = (t&7)*8;
  #pragma unroll
  for (int i=0;i<2;++i){
    int r = wr + i*32;
    union{ bf16 h[8]; uint4 u; } p;
    #pragma unroll
    for (int j=0;j<8;++j) p.h[j] = (bf16)sF[r][wc8+j];
    *(uint4*)(xb + (size_t)(n0+r)*1024 + c0 + wc8) = p.u;
  }
  #pragma unroll
  for (int i=0;i<2;++i){
    int c = wr + i*32;
    union{ bf16 h[8]; uint4 u; } p;
    #pragma unroll
    for (int j=0;j<8;++j) p.h[j] = (bf16)sF[wc8+j][c];
    *(uint4*)(xT + (size_t)(c0+c)*4096 + n0 + wc8) = p.u;
  }
}

// ---------- transpose + cast: WT[c][r] = W[r][c] ----------
__global__ __launch_bounds__(256) void k_transpose(const float* __restrict__ W, bf16* __restrict__ WT,
                                                   int R, int Ccols){
  __shared__ float tile[32][33];
  int bc = blockIdx.x*32, br = blockIdx.y*32;
  int lc = threadIdx.x & 31, lr = threadIdx.x >> 5;
  #pragma unroll
  for (int i=0;i<4;i++){
    int r = lr + i*8;
    tile[r][lc] = W[(size_t)(br+r)*Ccols + bc + lc];
  }
  __syncthreads();
  #pragma unroll
  for (int i=0;i<4;i++){
    int r = lr + i*8;
    WT[(size_t)(bc+r)*R + br + lc] = (bf16)tile[lc][r];
  }
}

// =====================================================================
// 128x128-tile bf16 GEMM (r1 structure), batched via z.
// =====================================================================
__global__ __launch_bounds__(256) void k_gemm128(
    const bf16* __restrict__ A, const bf16* __restrict__ BT, bf16* __restrict__ C,
    int N, int K, int lda, int ldb,
    size_t As, size_t Bs, size_t Cs)
{
  A += blockIdx.z*As; BT += blockIdx.z*Bs; C += blockIdx.z*Cs;
  __shared__ __align__(16) bf16 sA[128*64];
  __shared__ __align__(16) bf16 sB[128*64];
  const int t = threadIdx.x, w = t>>6, l = t&63;
  const int bm = blockIdx.y*128, bn = blockIdx.x*128;
  const int wr = (w>>1)*64, wc = (w&1)*64;
  f32x4 acc[4][4] = {};
  const int srow = l>>3;
  const int scol = ((l&7) ^ (l>>3))*8;
  const int nk = K>>6;
  for (int kt=0; kt<nk; ++kt) {
    const int k0 = kt*64;
    #pragma unroll
    for (int i=0;i<4;++i){
      int c = w*4+i;
      int row = c*8 + srow;
      gload_lds16(A  + (size_t)(bm+row)*lda + k0 + scol, (char*)sA + c*1024);
      gload_lds16(BT + (size_t)(bn+row)*ldb + k0 + scol, (char*)sB + c*1024);
    }
    __syncthreads();
    #pragma unroll
    for (int kk=0; kk<64; kk+=32) {
      bf16x8 af[4], bfr[4];
      const int xr = ((kk + 8*(l>>4))*2) ^ ((l&7)<<4);
      #pragma unroll
      for (int mf=0;mf<4;++mf){
        int row = wr + mf*16 + (l&15);
        af[mf] = *(const bf16x8*)((const char*)sA + row*128 + xr);
      }
      #pragma unroll
      for (int nf=0;nf<4;++nf){
        int row = wc + nf*16 + (l&15);
        bfr[nf] = *(const bf16x8*)((const char*)sB + row*128 + xr);
      }
      #pragma unroll
      for (int mf=0;mf<4;++mf)
        #pragma unroll
        for (int nf=0;nf<4;++nf)
          acc[mf][nf] = __builtin_amdgcn_mfma_f32_16x16x32_bf16(af[mf], bfr[nf], acc[mf][nf], 0,0,0);
    }
    __syncthreads();
  }
  #pragma unroll
  for (int mf=0;mf<4;++mf)
    #pragma unroll
    for (int nf=0;nf<4;++nf)
      #pragma unroll
      for (int r=0;r<4;++r){
        int row = bm + wr + mf*16 + (l>>4)*4 + r;
        int col = bn + wc + nf*16 + (l&15);
        C[(size_t)row*N + col] = (bf16)acc[mf][nf][r];
      }
}

// =====================================================================
// Gram split-K, NO XCD remap (A/B vs r9): grid (36,8,2) =
// (tile t36, batch, K-half). Block computes upper-tri tile (i,j) over
// its K-half, writes fp32 partial.
// =====================================================================
__global__ __launch_bounds__(256) void k_gramsplit(const bf16* __restrict__ xT, float* __restrict__ Gp){
  const int t36o = blockIdx.x;
  const int b = blockIdx.y;
  const int half = blockIdx.z;
  int t36 = t36o;
  int i = 0;
  while (t36 >= 8 - i){ t36 -= 8 - i; ++i; }
  const int j = i + t36;                     // i <= j
  const bf16* A = xT + (size_t)b*4194304;
  float* P = Gp + ((size_t)((half*8 + b)*36 + t36o))*16384;
  const int bm = i*128, bn = j*128;
  const int kbase = half*2048;

  __shared__ __align__(16) bf16 sA[128*64];
  __shared__ __align__(16) bf16 sB[128*64];
  const int t = threadIdx.x, w = t>>6, l = t&63;
  const int wr = (w>>1)*64, wc = (w&1)*64;
  f32x4 acc[4][4] = {};
  const int srow = l>>3;
  const int scol = ((l&7) ^ (l>>3))*8;
  for (int kt=0; kt<32; ++kt) {
    const int k0 = kbase + kt*64;
    #pragma unroll
    for (int ii=0;ii<4;++ii){
      int c = w*4+ii;
      int row = c*8 + srow;
      gload_lds16(A + (size_t)(bm+row)*4096 + k0 + scol, (char*)sA + c*1024);
      gload_lds16(A + (size_t)(bn+row)*4096 + k0 + scol, (char*)sB + c*1024);
    }
    __syncthreads();
    #pragma unroll
    for (int kk=0; kk<64; kk+=32) {
      bf16x8 af[4], bfr[4];
      const int xr = ((kk + 8*(l>>4))*2) ^ ((l&7)<<4);
      #pragma unroll
      for (int mf=0;mf<4;++mf)
        af[mf] = *(const bf16x8*)((const char*)sA + (wr+mf*16+(l&15))*128 + xr);
      #pragma unroll
      for (int nf=0;nf<4;++nf)
        bfr[nf] = *(const bf16x8*)((const char*)sB + (wc+nf*16+(l&15))*128 + xr);
      #pragma unroll
      for (int mf=0;mf<4;++mf)
        #pragma unroll
        for (int nf=0;nf<4;++nf)
          acc[mf][nf] = __builtin_amdgcn_mfma_f32_16x16x32_bf16(af[mf], bfr[nf], acc[mf][nf], 0,0,0);
    }
    __syncthreads();
  }
  #pragma unroll
  for (int mf=0;mf<4;++mf)
    #pragma unroll
    for (int nf=0;nf<4;++nf)
      #pragma unroll
      for (int r=0;r<4;++r)
        P[(wr + mf*16 + (l>>4)*4 + r)*128 + wc + nf*16 + (l&15)] = acc[mf][nf][r];
}

// =====================================================================
// Gram reduce: sum 2 fp32 partials -> bf16 tile + mirrored tile.
// =====================================================================
__global__ __launch_bounds__(256) void k_gramreduce(const float* __restrict__ Gp, bf16* __restrict__ Gram){
  const int b = blockIdx.y;
  const int t36o = blockIdx.x;
  int t36 = t36o;
  int i = 0;
  while (t36 >= 8 - i){ t36 -= 8 - i; ++i; }
  const int j = i + t36;
  const float* P0 = Gp + ((size_t)(b*36) + t36o)*16384;
  const float* P1 = Gp + ((size_t)((8+b)*36) + t36o)*16384;
  bf16* C = Gram + (size_t)b*1048576;
  const int bm = i*128, bn = j*128;
  __shared__ float sT[128][129];
  const int t = threadIdx.x;
  const int rr = t>>4, cc = (t&15)*8;
  #pragma unroll
  for (int ch=0; ch<8; ++ch){
    const int row = ch*16 + rr;
    const int idx = row*128 + cc;
    float4 a0 = *(const float4*)(P0+idx), a1 = *(const float4*)(P0+idx+4);
    float4 b0 = *(const float4*)(P1+idx), b1 = *(const float4*)(P1+idx+4);
    float s[8] = {a0.x+b0.x, a0.y+b0.y, a0.z+b0.z, a0.w+b0.w,
                  a1.x+b1.x, a1.y+b1.y, a1.z+b1.z, a1.w+b1.w};
    union{ bf16 h[8]; uint4 u; } p;
    #pragma unroll
    for (int k=0;k<8;++k) p.h[k] = (bf16)s[k];
    *(uint4*)(C + (size_t)(bm+row)*1024 + bn + cc) = p.u;
    if (i != j){
      #pragma unroll
      for (int k=0;k<8;++k) sT[row][cc+k] = s[k];
    }
  }
  if (i == j) return;
  __syncthreads();
  #pragma unroll
  for (int ch=0; ch<8; ++ch){
    const int c = ch*16 + rr;
    union{ bf16 h[8]; uint4 u; } p;
    #pragma unroll
    for (int k=0;k<8;++k) p.h[k] = (bf16)sT[cc+k][c];
    *(uint4*)(C + (size_t)(bn+c)*1024 + bm + cc) = p.u;
  }
}

// =====================================================================
// 256x256-tile pipelined GEMM (r3 structure), fused epilogue.
// =====================================================================
__global__ __launch_bounds__(512, 2) void k_gemm256(
    const bf16* __restrict__ A, const bf16* __restrict__ BT, bf16* __restrict__ C,
    int N, int K,
    const float* __restrict__ bias, const bf16* __restrict__ resid,
    size_t As, size_t Bs, size_t Cs, size_t Rs)
{
  A += blockIdx.z*As; BT += blockIdx.z*Bs; C += blockIdx.z*Cs; resid += blockIdx.z*Rs;
  __shared__ __align__(16) bf16 lds[2][2][256*64];
  bf16* bA0 = &lds[0][0][0]; bf16* bB0 = &lds[0][1][0];
  bf16* bA1 = &lds[1][0][0]; bf16* bB1 = &lds[1][1][0];

  const int t = threadIdx.x, w = t>>6, l = t&63;
  const int wm = w>>2, wn = w&3;

  const int nwg = gridDim.x * gridDim.y;
  const int orig = blockIdx.y * gridDim.x + blockIdx.x;
  const int q = nwg >> 3, r = nwg & 7;
  const int xcd = orig & 7, loc = orig >> 3;
  const int swz = (xcd < r ? xcd*(q+1) : r*(q+1) + (xcd-r)*q) + loc;
  const int bx = swz % gridDim.x, by = swz / gridDim.x;
  const int bm = by*256, bn = bx*256;

  const int co0 = (16*(l>>4)) ^ ((l&7)<<4);
  const int co1 = (64 + 16*(l>>4)) ^ ((l&7)<<4);

  auto stageA = [&](const bf16* G, bf16* Ldst, int j, int k0){
    int row = wm*128 + wn*32 + j*8 + (l>>3);
    int col = 8*((l&7) ^ (l>>3));
    gload_lds16(G + (size_t)(bm + row)*K + k0 + col,
                Ldst + (wm*128 + wn*32 + j*8)*64);
  };
  auto stageB = [&](const bf16* G, bf16* Ldst, int j, int k0){
    int row = j*64 + w*8 + (l>>3);
    int col = 8*((l&7) ^ (l>>3));
    gload_lds16(G + (size_t)(bn + row)*K + k0 + col,
                Ldst + (j*64 + w*8)*64);
  };

#define RD_AA(dst, qd, base) {                                                  \
    const int r0 = wm*128 + (qd)*32 + (l&15);                                   \
    dst[0][0] = *(const bf16x8*)((const char*)(base) + (r0   )*128 + co0);      \
    dst[0][1] = *(const bf16x8*)((const char*)(base) + (r0   )*128 + co1);      \
    dst[1][0] = *(const bf16x8*)((const char*)(base) + (r0+16)*128 + co0);      \
    dst[1][1] = *(const bf16x8*)((const char*)(base) + (r0+16)*128 + co1);      \
  }

#define MFMA_Q(P, AA) {                                                         \
    __builtin_amdgcn_s_setprio(1);                                              \
    _Pragma("unroll")                                                           \
    for (int kk=0;kk<2;++kk)                                                    \
      _Pragma("unroll")                                                         \
      for (int i=0;i<2;++i)                                                     \
        _Pragma("unroll")                                                       \
        for (int nf=0;nf<4;++nf)                                                \
          acc[2*(P)+i][nf] = __builtin_amdgcn_mfma_f32_16x16x32_bf16(           \
              AA[i][kk], bfr[nf][kk], acc[2*(P)+i][nf], 0,0,0);                 \
    __builtin_amdgcn_s_setprio(0);                                              \
  }

#define BAR asm volatile("s_barrier" ::: "memory")

  f32x4 acc[8][4] = {};
  const int NT = K >> 6;

  #pragma unroll
  for (int j=0;j<4;++j) stageA(A, bA0, j, 0);
  #pragma unroll
  for (int j=0;j<4;++j) stageB(BT, bB0, j, 0);
  __builtin_amdgcn_sched_barrier(0);
  if (NT > 1){
    #pragma unroll
    for (int j=0;j<4;++j) stageB(BT, bB1, j, 64);
    asm volatile("s_waitcnt vmcnt(4)" ::: "memory");
  } else {
    asm volatile("s_waitcnt vmcnt(0)" ::: "memory");
  }
  BAR;

  bf16x8 aaA[2][2], aaB[2][2];
  RD_AA(aaA, wn, bA0);

  for (int T = 0; T < NT; ++T){
    bf16* sA  = (T&1) ? bA1 : bA0;
    bf16* sB  = (T&1) ? bB1 : bB0;
    bf16* sAn = (T&1) ? bA0 : bA1;
    const int kA = (T+1)<<6, kB = (T+2)<<6;
    const bool stA = (T+1) < NT, stB = (T+2) < NT;

    bf16x8 bfr[4][2];
    const int rb = wn*64 + (l&15);
    #pragma unroll
    for (int nf=0;nf<4;++nf){
      bfr[nf][0] = *(const bf16x8*)((const char*)sB + (rb+nf*16)*128 + co0);
      bfr[nf][1] = *(const bf16x8*)((const char*)sB + (rb+nf*16)*128 + co1);
    }

    RD_AA(aaB, (wn+1)&3, sA);
    if (stA){ stageA(A, sAn, 0, kA); stageA(A, sAn, 1, kA); }
    BAR; MFMA_Q(0, aaA); BAR;

    RD_AA(aaA, (wn+2)&3, sA);
    if (stA){ stageA(A, sAn, 2, kA); stageA(A, sAn, 3, kA); }
    BAR; MFMA_Q(1, aaB); BAR;

    RD_AA(aaB, (wn+3)&3, sA);
    if (stB){ stageB(BT, sB, 0, kB); stageB(BT, sB, 1, kB); }
    BAR; MFMA_Q(2, aaA); BAR;

    if (stB){
      stageB(BT, sB, 2, kB); stageB(BT, sB, 3, kB);
      asm volatile("s_waitcnt vmcnt(4)" ::: "memory");
    } else {
      asm volatile("s_waitcnt vmcnt(0)" ::: "memory");
    }
    if (stA) RD_AA(aaA, wn, sAn);
    BAR; MFMA_Q(3, aaB); BAR;
  }
#undef RD_AA
#undef MFMA_Q
#undef BAR

  #pragma unroll
  for (int P=0; P<4; ++P){
    const int qd = (P+wn)&3;
    #pragma unroll
    for (int i=0;i<2;++i){
      #pragma unroll
      for (int nf=0; nf<4; ++nf){
        #pragma unroll
        for (int r2=0; r2<4; ++r2){
          int row = bm + wm*128 + qd*32 + i*16 + (l>>4)*4 + r2;
          int col = bn + wn*64 + nf*16 + (l&15);
          float v = acc[2*P+i][nf][r2] + bias[col] + (float)resid[(size_t)row*N + col];
          C[(size_t)row*N + col] = (bf16)v;
        }
      }
    }
  }
}

// ---------- S partials split-K 8: Sp[(ks*128+bg)*4096 + d*64+e] ----------
__global__ __launch_bounds__(256) void k_sgemm64(const bf16* __restrict__ T2, const bf16* __restrict__ WqkvT,
                                                 float* __restrict__ Sp){
  const int ks = blockIdx.x, bg = blockIdx.y, b = bg>>4, g = bg&15;
  const bf16* Arows = T2 + (size_t)b*1048576 + (size_t)(g*64)*1024;
  const bf16* Brows = WqkvT + (size_t)(2048 + g*64)*1024;
  __shared__ __align__(16) bf16 sA[64*64];
  __shared__ __align__(16) bf16 sB[64*64];
  const int t = threadIdx.x, w = t>>6, l = t&63;
  const int srow = l>>3, scol = ((l&7)^(l>>3))*8;
  f32x4 acc[4] = {};
  for (int kt=0; kt<2; ++kt){
    const int k0 = ks*128 + kt*64;
    gload_lds16(Arows + (size_t)(w*8+srow)*1024 + k0 + scol,      sA + (w*8)*64);
    gload_lds16(Arows + (size_t)(32+w*8+srow)*1024 + k0 + scol,   sA + (32+w*8)*64);
    gload_lds16(Brows + (size_t)(w*8+srow)*1024 + k0 + scol,      sB + (w*8)*64);
    gload_lds16(Brows + (size_t)(32+w*8+srow)*1024 + k0 + scol,   sB + (32+w*8)*64);
    __syncthreads();
    #pragma unroll
    for (int kk=0; kk<64; kk+=32){
      const int xr = ((kk + 8*(l>>4))*2) ^ ((l&7)<<4);
      bf16x8 af = *(const bf16x8*)((const char*)sA + (w*16+(l&15))*128 + xr);
      #pragma unroll
      for (int nf=0; nf<4; ++nf){
        bf16x8 bfv = *(const bf16x8*)((const char*)sB + (nf*16+(l&15))*128 + xr);
        acc[nf] = __builtin_amdgcn_mfma_f32_16x16x32_bf16(af, bfv, acc[nf], 0,0,0);
      }
    }
    __syncthreads();
  }
  float* o = Sp + ((size_t)ks*128 + bg)*4096;
  #pragma unroll
  for (int reg=0; reg<4; ++reg){
    const int row = w*16 + (l>>4)*4 + reg;
    #pragma unroll
    for (int nf=0; nf<4; ++nf)
      o[row*64 + nf*16 + (l&15)] = acc[nf][reg];
  }
}

// ---------- reduce 8 partials, scale, row softmax -> Aatt bf16 (r5-proven) ----------
__global__ __launch_bounds__(256) void k_softmax(const float* __restrict__ Sp, bf16* __restrict__ P){
  const int bg = blockIdx.x;
  __shared__ float S[64][64];
  const int t = threadIdx.x;
  for (int idx=t; idx<4096; idx+=256){
    float s = 0;
    #pragma unroll
    for (int ks=0;ks<8;++ks) s += Sp[((size_t)ks*128+bg)*4096 + idx];
    S[idx>>6][idx&63] = s * 0.125f;
  }
  __syncthreads();
  const int row = t>>2, qd = t&3;
  float m = -3.4e38f;
  #pragma unroll
  for (int j=0;j<16;++j) m = fmaxf(m, S[row][qd*16+j]);
  m = fmaxf(m, __shfl_xor(m,1));
  m = fmaxf(m, __shfl_xor(m,2));
  float e[16]; float sum = 0.f;
  #pragma unroll
  for (int j=0;j<16;++j){ e[j] = __expf(S[row][qd*16+j]-m); sum += e[j]; }
  sum += __shfl_xor(sum,1);
  sum += __shfl_xor(sum,2);
  float inv = 1.0f/sum;
  #pragma unroll
  for (int j=0;j<16;++j) P[(size_t)bg*4096 + row*64 + qd*16 + j] = (bf16)(e[j]*inv);
}

// ---------- U[c][g*64+d] = sum_e Wq[c][g*64+e] * Aatt_bg[d][e] ----------
__global__ __launch_bounds__(256) void k_applyW(const bf16* __restrict__ Wqkvb, const bf16* __restrict__ Aatt,
                                                bf16* __restrict__ U){
  const int bg = blockIdx.y, b = bg>>4, g = bg&15;
  const int m0 = blockIdx.x*128;
  __shared__ __align__(16) bf16 Pl[64][72];
  const int t = threadIdx.x, w = t>>6, l = t&63;
  for (int idx=t; idx<1024; idx+=256){
    int r2 = idx>>4, c4 = (idx&15)*4;
    *(uint2*)&Pl[r2][c4] = *(const uint2*)&Aatt[(size_t)bg*4096 + r2*64 + c4];
  }
  __syncthreads();
  f32x4 acc[2][4] = {};
  const bf16* Ab = Wqkvb + (size_t)(m0 + w*32)*3072 + g*64;
  #pragma unroll
  for (int kk=0; kk<64; kk+=32){
    bf16x8 af[2], pf[4];
    #pragma unroll
    for (int mf=0;mf<2;++mf)
      af[mf] = *(const bf16x8*)(Ab + (size_t)(mf*16 + (l&15))*3072 + kk + 8*(l>>4));
    #pragma unroll
    for (int nf=0;nf<4;++nf)
      pf[nf] = *(const bf16x8*)&Pl[nf*16 + (l&15)][kk + 8*(l>>4)];
    #pragma unroll
    for (int mf=0;mf<2;++mf)
      #pragma unroll
      for (int nf=0;nf<4;++nf)
        acc[mf][nf] = __builtin_amdgcn_mfma_f32_16x16x32_bf16(af[mf], pf[nf], acc[mf][nf], 0,0,0);
  }
  #pragma unroll
  for (int mf=0;mf<2;++mf)
    #pragma unroll
    for (int nf=0;nf<4;++nf)
      #pragma unroll
      for (int r=0;r<4;++r){
        int rowc = m0 + w*32 + mf*16 + (l>>4)*4 + r;
        int col = g*64 + nf*16 + (l&15);
        U[(size_t)b*1048576 + (size_t)rowc*1024 + col] = (bf16)acc[mf][nf][r];
      }
}

// ---------- LayerNorm: wave per row of 1024 ----------
__global__ __launch_bounds__(256) void k_ln(const bf16* __restrict__ h, const float* __restrict__ gamma,
                                            const float* __restrict__ beta, float* __restrict__ y){
  const int w = threadIdx.x>>6, l = threadIdx.x&63;
  const size_t row = (size_t)blockIdx.x*4 + w;
  const bf16* hr = h + row*1024 + l*16;
  uint4 p0 = *(const uint4*)hr;
  uint4 p1 = *(const uint4*)(hr+8);
  float v[16];
  const uint32_t* pw = (const uint32_t*)&p0;
  #pragma unroll
  for (int i=0;i<4;++i){ v[2*i] = bits2f(pw[i]<<16); v[2*i+1] = bits2f(pw[i]&0xffff0000u); }
  const uint32_t* pw1 = (const uint32_t*)&p1;
  #pragma unroll
  for (int i=0;i<4;++i){ v[8+2*i] = bits2f(pw1[i]<<16); v[8+2*i+1] = bits2f(pw1[i]&0xffff0000u); }
  float s=0.f, s2=0.f;
  #pragma unroll
  for (int i=0;i<16;++i){ s+=v[i]; s2+=v[i]*v[i]; }
  #pragma unroll
  for (int off=1; off<64; off<<=1){ s += __shfl_xor(s,off); s2 += __shfl_xor(s2,off); }
  float mu = s*(1.0f/1024.0f);
  float var = s2*(1.0f/1024.0f) - mu*mu;
  float rinv = rsqrtf(var + 1e-5f);
  const float* gp = gamma + l*16; const float* bp = beta + l*16;
  float o[16];
  #pragma unroll
  for (int i=0;i<16;++i) o[i] = gp[i]*(v[i]-mu)*rinv + bp[i];
  float* yr = y + row*1024 + l*16;
  #pragma unroll
  for (int i=0;i<4;++i) ((float4*)yr)[i] = *(float4*)&o[4*i];
}

extern "C" void kernel_launch(void* const* d_in, const int* in_sizes, int n_in,
                              void* d_out, int out_size, void* d_ws, size_t ws_size,
                              hipStream_t stream){
  const float* x     = (const float*)d_in[0];
  const float* Wqkv  = (const float*)d_in[1];
  const float* Wproj = (const float*)d_in[2];
  const float* bproj = (const float*)d_in[3];
  const float* gamma = (const float*)d_in[4];
  const float* beta  = (const float*)d_in[5];
  float* y = (float*)d_out;

  char* ws = (char*)d_ws;
  size_t off = 0;
  auto alloc = [&](size_t bytes)->void*{ void* p = ws + off; off += (bytes + 255) & ~(size_t)255; return p; };
  bf16*  xb     = (bf16*) alloc((size_t)32768*1024*2);   // 67.1 MB
  bf16*  xT     = (bf16*) alloc((size_t)8*1024*4096*2);  // 67.1 MB (reused as h)
  bf16*  Wqkvb  = (bf16*) alloc((size_t)1024*3072*2);
  bf16*  WqkvT  = (bf16*) alloc((size_t)3072*1024*2);
  bf16*  WprojT = (bf16*) alloc((size_t)1024*1024*2);
  bf16*  Gram   = (bf16*) alloc((size_t)8*1024*1024*2);  // 16.8 MB
  bf16*  T2     = (bf16*) alloc((size_t)8*1024*1024*2);
  bf16*  Aatt   = (bf16*) alloc((size_t)128*64*64*2);
  bf16*  U      = (bf16*) alloc((size_t)8*1024*1024*2);
  bf16*  WeffT  = (bf16*) alloc((size_t)8*1024*1024*2);
  float* Gpart  = (float*)alloc((size_t)2*8*36*16384*4); // 37.7 MB fp32 partials
  bf16*  h      = xT;   // xT dead after Gram
  float* Sp     = Gpart; // Gpart dead after gramreduce; reuse for S partials (16.8 MB)

  const size_t MB1 = 1048576;

  k_castT<<<dim3(16,64,8),256,0,stream>>>(x, xb, xT);
  k_cast<<<1536,256,0,stream>>>(Wqkv, Wqkvb, 3145728);
  k_transpose<<<dim3(96,32),256,0,stream>>>(Wqkv, WqkvT, 1024, 3072);
  k_transpose<<<dim3(32,32),256,0,stream>>>(Wproj, WprojT, 1024, 1024);
  // Gram_b = xT_b @ xT_b^T (symmetric upper tiles, split-K 2, NO remap)
  k_gramsplit<<<dim3(36,8,2),256,0,stream>>>(xT, Gpart);
  k_gramreduce<<<dim3(36,8),256,0,stream>>>(Gpart, Gram);
  // T2_b = Wk^T @ Gram_b  [1024x1024], K=1024  (Gram symmetric)
  k_gemm128<<<dim3(8,8,8),256,0,stream>>>(WqkvT + (size_t)1024*1024, Gram, T2, 1024, 1024, 1024, 1024,
                                          0, MB1, MB1);
  // S partials (split-K 8) + softmax -> Aatt
  k_sgemm64<<<dim3(8,128),256,0,stream>>>(T2, WqkvT, Sp);
  k_softmax<<<128,256,0,stream>>>(Sp, Aatt);
  // U_b[:, g-block] = Wq_g @ Aatt_bg^T
  k_applyW<<<dim3(8,128),256,0,stream>>>(Wqkvb, Aatt, U);
  // WeffT_b = WprojT @ U_b^T  [1024x1024], K=1024
  k_gemm128<<<dim3(8,8,8),256,0,stream>>>(WprojT, U, WeffT, 1024, 1024, 1024, 1024,
                                          0, MB1, MB1);
  // h_b = xb_b @ WeffT_b^T + bproj + xb_b   [4096x1024] per batch
  k_gemm256<<<dim3(4,16,8),512,0,stream>>>(xb, WeffT, h, 1024, 1024, bproj, xb,
                                           (size_t)4096*1024, MB1, (size_t)4096*1024, (size_t)4096*1024);
  k_ln<<<8192,256,0,stream>>>(h, gamma, beta, y);
}

// Round 11
// 365.364 us; speedup vs baseline: 1.0188x; 1.0188x over previous
//
#include <hip/hip_runtime.h>
#include <cstdint>

typedef __bf16 bf16;
typedef __bf16 bf16x8 __attribute__((ext_vector_type(8)));
typedef float f32x4 __attribute__((ext_vector_type(4)));

#define DEVI __device__ __forceinline__

DEVI float bits2f(uint32_t u){ union{uint32_t u;float f;}x; x.u=u; return x.f; }
DEVI uint32_t packbf2(float a, float b){
  union{ bf16 h[2]; uint32_t u; } p; p.h[0]=(bf16)a; p.h[1]=(bf16)b; return p.u;
}

DEVI void gload_lds16(const void* g, void* l){
  __builtin_amdgcn_global_load_lds(
    (const __attribute__((address_space(1))) uint32_t*)g,
    (__attribute__((address_space(3))) uint32_t*)l, 16, 0, 0);
}

// ---------- cast fp32 -> bf16, 8 elems/thread ----------
__global__ __launch_bounds__(256) void k_cast(const float* __restrict__ x, bf16* __restrict__ o, int n){
  int i = (blockIdx.x*256 + threadIdx.x)*8;
  if (i >= n) return;
  float4 a = *(const float4*)(x+i);
  float4 b = *(const float4*)(x+i+4);
  union { bf16 h[8]; uint4 u; } r;
  r.h[0]=(bf16)a.x; r.h[1]=(bf16)a.y; r.h[2]=(bf16)a.z; r.h[3]=(bf16)a.w;
  r.h[4]=(bf16)b.x; r.h[5]=(bf16)b.y; r.h[6]=(bf16)b.z; r.h[7]=(bf16)b.w;
  *(uint4*)(o+i) = r.u;
}

// ---------- fused: read x fp32 once -> xb (bf16) + xT (bf16 transposed) ----------
__global__ __launch_bounds__(256) void k_castT(const float* __restrict__ x, bf16* __restrict__ xb,
                                               bf16* __restrict__ xT){
  const int b = blockIdx.z;
  x  += (size_t)b*4194304; xb += (size_t)b*4194304; xT += (size_t)b*4194304;
  const int n0 = blockIdx.y*64, c0 = blockIdx.x*64;
  __shared__ float sF[64][65];
  const int t = threadIdx.x;
  const int lr = t>>4, lc4 = (t&15)*4;
  #pragma unroll
  for (int i=0;i<4;++i){
    int r = lr + i*16;
    float4 v = *(const float4*)(x + (size_t)(n0+r)*1024 + c0 + lc4);
    sF[r][lc4+0]=v.x; sF[r][lc4+1]=v.y; sF[r][lc4+2]=v.z; sF[r][lc4+3]=v.w;
  }
  __syncthreads();
  const int wr = t>>3, wc8 = (t&7)*8;
  #pragma unroll
  for (int i=0;i<2;++i){
    int r = wr + i*32;
    union{ bf16 h[8]; uint4 u; } p;
    #pragma unroll
    for (int j=0;j<8;++j) p.h[j] = (bf16)sF[r][wc8+j];
    *(uint4*)(xb + (size_t)(n0+r)*1024 + c0 + wc8) = p.u;
  }
  #pragma unroll
  for (int i=0;i<2;++i){
    int c = wr + i*32;
    union{ bf16 h[8]; uint4 u; } p;
    #pragma unroll
    for (int j=0;j<8;++j) p.h[j] = (bf16)sF[wc8+j][c];
    *(uint4*)(xT + (size_t)(c0+c)*4096 + n0 + wc8) = p.u;
  }
}

// ---------- transpose + cast: WT[c][r] = W[r][c] ----------
__global__ __launch_bounds__(256) void k_transpose(const float* __restrict__ W, bf16* __restrict__ WT,
                                                   int R, int Ccols){
  __shared__ float tile[32][33];
  int bc = blockIdx.x*32, br = blockIdx.y*32;
  int lc = threadIdx.x & 31, lr = threadIdx.x >> 5;
  #pragma unroll
  for (int i=0;i<4;i++){
    int r = lr + i*8;
    tile[r][lc] = W[(size_t)(br+r)*Ccols + bc + lc];
  }
  __syncthreads();
  #pragma unroll
  for (int i=0;i<4;i++){
    int r = lr + i*8;
    WT[(size_t)(bc+r)*R + br + lc] = (bf16)tile[lc][r];
  }
}

// =====================================================================
// 128x128-tile bf16 GEMM (r1 structure), batched via z.
// EPI=1: C = bf16(acc + bias[col] + resid[row][col]), resid bf16.
// =====================================================================
template<int EPI>
__global__ __launch_bounds__(256) void k_gemm128(
    const bf16* __restrict__ A, const bf16* __restrict__ BT, bf16* __restrict__ C,
    int N, int K, int lda, int ldb,
    size_t As, size_t Bs, size_t Cs,
    const float* __restrict__ bias, const bf16* __restrict__ resid, size_t Rs)
{
  A += blockIdx.z*As; BT += blockIdx.z*Bs; C += blockIdx.z*Cs;
  if (EPI==1) resid += blockIdx.z*Rs;
  __shared__ __align__(16) bf16 sA[128*64];
  __shared__ __align__(16) bf16 sB[128*64];
  const int t = threadIdx.x, w = t>>6, l = t&63;
  const int bm = blockIdx.y*128, bn = blockIdx.x*128;
  const int wr = (w>>1)*64, wc = (w&1)*64;
  f32x4 acc[4][4] = {};
  const int srow = l>>3;
  const int scol = ((l&7) ^ (l>>3))*8;
  const int nk = K>>6;
  for (int kt=0; kt<nk; ++kt) {
    const int k0 = kt*64;
    #pragma unroll
    for (int i=0;i<4;++i){
      int c = w*4+i;
      int row = c*8 + srow;
      gload_lds16(A  + (size_t)(bm+row)*lda + k0 + scol, (char*)sA + c*1024);
      gload_lds16(BT + (size_t)(bn+row)*ldb + k0 + scol, (char*)sB + c*1024);
    }
    __syncthreads();
    #pragma unroll
    for (int kk=0; kk<64; kk+=32) {
      bf16x8 af[4], bfr[4];
      const int xr = ((kk + 8*(l>>4))*2) ^ ((l&7)<<4);
      #pragma unroll
      for (int mf=0;mf<4;++mf){
        int row = wr + mf*16 + (l&15);
        af[mf] = *(const bf16x8*)((const char*)sA + row*128 + xr);
      }
      #pragma unroll
      for (int nf=0;nf<4;++nf){
        int row = wc + nf*16 + (l&15);
        bfr[nf] = *(const bf16x8*)((const char*)sB + row*128 + xr);
      }
      #pragma unroll
      for (int mf=0;mf<4;++mf)
        #pragma unroll
        for (int nf=0;nf<4;++nf)
          acc[mf][nf] = __builtin_amdgcn_mfma_f32_16x16x32_bf16(af[mf], bfr[nf], acc[mf][nf], 0,0,0);
    }
    __syncthreads();
  }
  #pragma unroll
  for (int mf=0;mf<4;++mf)
    #pragma unroll
    for (int nf=0;nf<4;++nf)
      #pragma unroll
      for (int r=0;r<4;++r){
        int row = bm + wr + mf*16 + (l>>4)*4 + r;
        int col = bn + wc + nf*16 + (l&15);
        float v = acc[mf][nf][r];
        if (EPI==1) v += bias[col] + (float)resid[(size_t)row*N + col];
        C[(size_t)row*N + col] = (bf16)v;
      }
}

// =====================================================================
// Gram = xT_b @ xT_b^T (symmetric): upper-triangle 128^2 tiles (36/batch),
// 8 WAVES per block (512 thr) for latency hiding; mirror via LDS transpose.
// Grid (36,8). Wave (wm=w>>1, wn=w&1) owns rows wm*32..+32, cols wn*64..+64.
// =====================================================================
__global__ __launch_bounds__(512) void k_gramsym(const bf16* __restrict__ xT, bf16* __restrict__ Gram){
  const int t36o = blockIdx.x, b = blockIdx.y;
  int t36 = t36o;
  int i = 0;
  while (t36 >= 8 - i){ t36 -= 8 - i; ++i; }
  const int j = i + t36;                     // i <= j
  const bf16* A = xT + (size_t)b*4194304;
  bf16* C = Gram + (size_t)b*1048576;
  const int bm = i*128, bn = j*128;

  __shared__ __align__(16) bf16 sAB[16384];  // 32 KiB: sA|sB; reused as transpose buf
  bf16* sA = sAB; bf16* sB = sAB + 8192;
  const int t = threadIdx.x, w = t>>6, l = t&63;
  const int wm = w>>1, wn = w&1;
  f32x4 acc[2][4] = {};
  const int srow = l>>3;
  const int scol = ((l&7) ^ (l>>3))*8;
  for (int kt=0; kt<64; ++kt) {
    const int k0 = kt*64;
    #pragma unroll
    for (int ii=0;ii<2;++ii){
      int c = w*2+ii;                        // 0..15
      int row = c*8 + srow;
      gload_lds16(A + (size_t)(bm+row)*4096 + k0 + scol, (char*)sA + c*1024);
      gload_lds16(A + (size_t)(bn+row)*4096 + k0 + scol, (char*)sB + c*1024);
    }
    __syncthreads();
    #pragma unroll
    for (int kk=0; kk<64; kk+=32) {
      bf16x8 af[2], bfr[4];
      const int xr = ((kk + 8*(l>>4))*2) ^ ((l&7)<<4);
      #pragma unroll
      for (int mf=0;mf<2;++mf)
        af[mf] = *(const bf16x8*)((const char*)sA + (wm*32+mf*16+(l&15))*128 + xr);
      #pragma unroll
      for (int nf=0;nf<4;++nf)
        bfr[nf] = *(const bf16x8*)((const char*)sB + (wn*64+nf*16+(l&15))*128 + xr);
      #pragma unroll
      for (int mf=0;mf<2;++mf)
        #pragma unroll
        for (int nf=0;nf<4;++nf)
          acc[mf][nf] = __builtin_amdgcn_mfma_f32_16x16x32_bf16(af[mf], bfr[nf], acc[mf][nf], 0,0,0);
    }
    __syncthreads();
  }
  // normal write: C[bm+row][bn+col]
  #pragma unroll
  for (int mf=0;mf<2;++mf)
    #pragma unroll
    for (int nf=0;nf<4;++nf)
      #pragma unroll
      for (int r=0;r<4;++r){
        int row = bm + wm*32 + mf*16 + (l>>4)*4 + r;
        int col = bn + wn*64 + nf*16 + (l&15);
        C[(size_t)row*1024 + col] = (bf16)acc[mf][nf][r];
      }
  if (i == j) return;
  // mirror write: C[bn+col][bm+row] via LDS transpose, two 64-col halves.
  // tr layout: [64 cols][136 rows-padded] bf16 (272B stride).
  for (int h2=0; h2<2; ++h2){
    __syncthreads();
    if (wn == h2){
      #pragma unroll
      for (int mf=0;mf<2;++mf)
        #pragma unroll
        for (int nf=0;nf<4;++nf)
          #pragma unroll
          for (int p=0;p<2;++p){
            int col_local = nf*16 + (l&15);
            int rowb = wm*32 + mf*16 + (l>>4)*4 + 2*p;
            *(uint32_t*)((char*)sAB + (col_local*136 + rowb)*2) =
              packbf2(acc[mf][nf][2*p], acc[mf][nf][2*p+1]);
          }
    }
    __syncthreads();
    {
      int col_local = t>>3, sub = t&7;       // 64 cols x 8 subs of 16 rows
      const uint4* src = (const uint4*)((const char*)sAB + col_local*272 + sub*32);
      uint4 v0 = src[0], v1 = src[1];
      bf16* dst = C + (size_t)(bn + h2*64 + col_local)*1024 + bm + sub*16;
      ((uint4*)dst)[0]=v0; ((uint4*)dst)[1]=v1;
    }
  }
}

// ---------- fused S = scale * T2_g @ Wv_g^T + row softmax -> Aatt[bg][64][64] ----------
__global__ __launch_bounds__(256) void k_sgemm64(const bf16* __restrict__ T2, const bf16* __restrict__ WqkvT,
                                                 bf16* __restrict__ Aatt){
  const int bg = blockIdx.x, b = bg>>4, g = bg&15;
  const bf16* Arows = T2 + (size_t)b*1048576 + (size_t)(g*64)*1024;
  const bf16* Brows = WqkvT + (size_t)(2048 + g*64)*1024;
  __shared__ __align__(16) bf16 sA[64*64];
  __shared__ __align__(16) bf16 sB[64*64];
  const int t = threadIdx.x, w = t>>6, l = t&63;
  const int srow = l>>3, scol = ((l&7)^(l>>3))*8;
  f32x4 acc[4] = {};
  for (int kt=0; kt<16; ++kt){
    const int k0 = kt*64;
    gload_lds16(Arows + (size_t)(w*8+srow)*1024 + k0 + scol,      sA + (w*8)*64);
    gload_lds16(Arows + (size_t)(32+w*8+srow)*1024 + k0 + scol,   sA + (32+w*8)*64);
    gload_lds16(Brows + (size_t)(w*8+srow)*1024 + k0 + scol,      sB + (w*8)*64);
    gload_lds16(Brows + (size_t)(32+w*8+srow)*1024 + k0 + scol,   sB + (32+w*8)*64);
    __syncthreads();
    #pragma unroll
    for (int kk=0; kk<64; kk+=32){
      const int xr = ((kk + 8*(l>>4))*2) ^ ((l&7)<<4);
      bf16x8 af = *(const bf16x8*)((const char*)sA + (w*16+(l&15))*128 + xr);
      #pragma unroll
      for (int nf=0; nf<4; ++nf){
        bf16x8 bfv = *(const bf16x8*)((const char*)sB + (nf*16+(l&15))*128 + xr);
        acc[nf] = __builtin_amdgcn_mfma_f32_16x16x32_bf16(af, bfv, acc[nf], 0,0,0);
      }
    }
    __syncthreads();
  }
  #pragma unroll
  for (int reg=0; reg<4; ++reg){
    float m = -3.4e38f;
    #pragma unroll
    for (int nf=0; nf<4; ++nf) m = fmaxf(m, acc[nf][reg]);
    m = fmaxf(m, __shfl_xor(m,1)); m = fmaxf(m, __shfl_xor(m,2));
    m = fmaxf(m, __shfl_xor(m,4)); m = fmaxf(m, __shfl_xor(m,8));
    float e[4]; float s = 0.f;
    #pragma unroll
    for (int nf=0; nf<4; ++nf){ e[nf] = __expf((acc[nf][reg]-m)*0.125f); s += e[nf]; }
    s += __shfl_xor(s,1); s += __shfl_xor(s,2); s += __shfl_xor(s,4); s += __shfl_xor(s,8);
    const float inv = 1.0f/s;
    const int row = w*16 + (l>>4)*4 + reg;
    #pragma unroll
    for (int nf=0; nf<4; ++nf)
      Aatt[(size_t)bg*4096 + row*64 + nf*16 + (l&15)] = (bf16)(e[nf]*inv);
  }
}

// ---------- U[c][g*64+d] = sum_e Wq[c][g*64+e] * Aatt_bg[d][e] ----------
__global__ __launch_bounds__(256) void k_applyW(const bf16* __restrict__ Wqkvb, const bf16* __restrict__ Aatt,
                                                bf16* __restrict__ U){
  const int bg = blockIdx.y, b = bg>>4, g = bg&15;
  const int m0 = blockIdx.x*128;
  __shared__ __align__(16) bf16 Pl[64][72];
  const int t = threadIdx.x, w = t>>6, l = t&63;
  for (int idx=t; idx<1024; idx+=256){
    int r2 = idx>>4, c4 = (idx&15)*4;
    *(uint2*)&Pl[r2][c4] = *(const uint2*)&Aatt[(size_t)bg*4096 + r2*64 + c4];
  }
  __syncthreads();
  f32x4 acc[2][4] = {};
  const bf16* Ab = Wqkvb + (size_t)(m0 + w*32)*3072 + g*64;
  #pragma unroll
  for (int kk=0; kk<64; kk+=32){
    bf16x8 af[2], pf[4];
    #pragma unroll
    for (int mf=0;mf<2;++mf)
      af[mf] = *(const bf16x8*)(Ab + (size_t)(mf*16 + (l&15))*3072 + kk + 8*(l>>4));
    #pragma unroll
    for (int nf=0;nf<4;++nf)
      pf[nf] = *(const bf16x8*)&Pl[nf*16 + (l&15)][kk + 8*(l>>4)];
    #pragma unroll
    for (int mf=0;mf<2;++mf)
      #pragma unroll
      for (int nf=0;nf<4;++nf)
        acc[mf][nf] = __builtin_amdgcn_mfma_f32_16x16x32_bf16(af[mf], pf[nf], acc[mf][nf], 0,0,0);
  }
  #pragma unroll
  for (int mf=0;mf<2;++mf)
    #pragma unroll
    for (int nf=0;nf<4;++nf)
      #pragma unroll
      for (int r=0;r<4;++r){
        int rowc = m0 + w*32 + mf*16 + (l>>4)*4 + r;
        int col = g*64 + nf*16 + (l&15);
        U[(size_t)b*1048576 + (size_t)rowc*1024 + col] = (bf16)acc[mf][nf][r];
      }
}

// ---------- LayerNorm: wave per row of 1024 ----------
__global__ __launch_bounds__(256) void k_ln(const bf16* __restrict__ h, const float* __restrict__ gamma,
                                            const float* __restrict__ beta, float* __restrict__ y){
  const int w = threadIdx.x>>6, l = threadIdx.x&63;
  const size_t row = (size_t)blockIdx.x*4 + w;
  const bf16* hr = h + row*1024 + l*16;
  uint4 p0 = *(const uint4*)hr;
  uint4 p1 = *(const uint4*)(hr+8);
  float v[16];
  const uint32_t* pw = (const uint32_t*)&p0;
  #pragma unroll
  for (int i=0;i<4;++i){ v[2*i] = bits2f(pw[i]<<16); v[2*i+1] = bits2f(pw[i]&0xffff0000u); }
  const uint32_t* pw1 = (const uint32_t*)&p1;
  #pragma unroll
  for (int i=0;i<4;++i){ v[8+2*i] = bits2f(pw1[i]<<16); v[8+2*i+1] = bits2f(pw1[i]&0xffff0000u); }
  float s=0.f, s2=0.f;
  #pragma unroll
  for (int i=0;i<16;++i){ s+=v[i]; s2+=v[i]*v[i]; }
  #pragma unroll
  for (int off=1; off<64; off<<=1){ s += __shfl_xor(s,off); s2 += __shfl_xor(s2,off); }
  float mu = s*(1.0f/1024.0f);
  float var = s2*(1.0f/1024.0f) - mu*mu;
  float rinv = rsqrtf(var + 1e-5f);
  const float* gp = gamma + l*16; const float* bp = beta + l*16;
  float o[16];
  #pragma unroll
  for (int i=0;i<16;++i) o[i] = gp[i]*(v[i]-mu)*rinv + bp[i];
  float* yr = y + row*1024 + l*16;
  #pragma unroll
  for (int i=0;i<4;++i) ((float4*)yr)[i] = *(float4*)&o[4*i];
}

extern "C" void kernel_launch(void* const* d_in, const int* in_sizes, int n_in,
                              void* d_out, int out_size, void* d_ws, size_t ws_size,
                              hipStream_t stream){
  const float* x     = (const float*)d_in[0];
  const float* Wqkv  = (const float*)d_in[1];
  const float* Wproj = (const float*)d_in[2];
  const float* bproj = (const float*)d_in[3];
  const float* gamma = (const float*)d_in[4];
  const float* beta  = (const float*)d_in[5];
  float* y = (float*)d_out;

  char* ws = (char*)d_ws;
  size_t off = 0;
  auto alloc = [&](size_t bytes)->void*{ void* p = ws + off; off += (bytes + 255) & ~(size_t)255; return p; };
  bf16* xb     = (bf16*)alloc((size_t)32768*1024*2);   // 67.1 MB
  bf16* xT     = (bf16*)alloc((size_t)8*1024*4096*2);  // 67.1 MB (reused as h)
  bf16* Wqkvb  = (bf16*)alloc((size_t)1024*3072*2);
  bf16* WqkvT  = (bf16*)alloc((size_t)3072*1024*2);
  bf16* WprojT = (bf16*)alloc((size_t)1024*1024*2);
  bf16* Gram   = (bf16*)alloc((size_t)8*1024*1024*2);  // 16.8 MB
  bf16* T2     = (bf16*)alloc((size_t)8*1024*1024*2);
  bf16* Aatt   = (bf16*)alloc((size_t)128*64*64*2);
  bf16* U      = (bf16*)alloc((size_t)8*1024*1024*2);
  bf16* WeffT  = (bf16*)alloc((size_t)8*1024*1024*2);
  bf16* h      = xT;   // xT dead after Gram

  const size_t MB1 = 1048576;
  const size_t MB4 = (size_t)4096*1024;

  k_castT<<<dim3(16,64,8),256,0,stream>>>(x, xb, xT);
  k_cast<<<1536,256,0,stream>>>(Wqkv, Wqkvb, 3145728);
  k_transpose<<<dim3(96,32),256,0,stream>>>(Wqkv, WqkvT, 1024, 3072);
  k_transpose<<<dim3(32,32),256,0,stream>>>(Wproj, WprojT, 1024, 1024);
  // Gram_b = xT_b @ xT_b^T (symmetric upper tiles, 8-wave blocks)
  k_gramsym<<<dim3(36,8),512,0,stream>>>(xT, Gram);
  // T2_b = Wk^T @ Gram_b  [1024x1024], K=1024  (Gram symmetric)
  k_gemm128<0><<<dim3(8,8,8),256,0,stream>>>(WqkvT + (size_t)1024*1024, Gram, T2, 1024, 1024, 1024, 1024,
                                             0, MB1, MB1, nullptr, nullptr, 0);
  // S + softmax -> Aatt (fused)
  k_sgemm64<<<128,256,0,stream>>>(T2, WqkvT, Aatt);
  // U_b[:, g-block] = Wq_g @ Aatt_bg^T
  k_applyW<<<dim3(8,128),256,0,stream>>>(Wqkvb, Aatt, U);
  // WeffT_b = WprojT @ U_b^T  [1024x1024], K=1024
  k_gemm128<0><<<dim3(8,8,8),256,0,stream>>>(WprojT, U, WeffT, 1024, 1024, 1024, 1024,
                                             0, MB1, MB1, nullptr, nullptr, 0);
  // h_b = xb_b @ WeffT_b^T + bproj + xb_b   [4096x1024] per batch
  k_gemm128<1><<<dim3(8,32,8),256,0,stream>>>(xb, WeffT, h, 1024, 1024, 1024, 1024,
                                              MB4, MB1, MB4, bproj, xb, MB4);
  k_ln<<<8192,256,0,stream>>>(h, gamma, beta, y);
}

// Round 12
// 330.920 us; speedup vs baseline: 1.1248x; 1.1041x over previous
//
#include <hip/hip_runtime.h>
#include <cstdint>

typedef __bf16 bf16;
typedef __bf16 bf16x8 __attribute__((ext_vector_type(8)));
typedef float f32x4 __attribute__((ext_vector_type(4)));

#define DEVI __device__ __forceinline__

DEVI float bits2f(uint32_t u){ union{uint32_t u;float f;}x; x.u=u; return x.f; }

DEVI void gload_lds16(const void* g, void* l){
  __builtin_amdgcn_global_load_lds(
    (const __attribute__((address_space(1))) uint32_t*)g,
    (__attribute__((address_space(3))) uint32_t*)l, 16, 0, 0);
}

// ---------- cast fp32 -> bf16, 8 elems/thread ----------
__global__ __launch_bounds__(256) void k_cast(const float* __restrict__ x, bf16* __restrict__ o, int n){
  int i = (blockIdx.x*256 + threadIdx.x)*8;
  if (i >= n) return;
  float4 a = *(const float4*)(x+i);
  float4 b = *(const float4*)(x+i+4);
  union { bf16 h[8]; uint4 u; } r;
  r.h[0]=(bf16)a.x; r.h[1]=(bf16)a.y; r.h[2]=(bf16)a.z; r.h[3]=(bf16)a.w;
  r.h[4]=(bf16)b.x; r.h[5]=(bf16)b.y; r.h[6]=(bf16)b.z; r.h[7]=(bf16)b.w;
  *(uint4*)(o+i) = r.u;
}

// ---------- fused: read x fp32 once -> xb (bf16) + xT (bf16 transposed) ----------
__global__ __launch_bounds__(256) void k_castT(const float* __restrict__ x, bf16* __restrict__ xb,
                                               bf16* __restrict__ xT){
  const int b = blockIdx.z;
  x  += (size_t)b*4194304; xb += (size_t)b*4194304; xT += (size_t)b*4194304;
  const int n0 = blockIdx.y*64, c0 = blockIdx.x*64;
  __shared__ float sF[64][65];
  const int t = threadIdx.x;
  const int lr = t>>4, lc4 = (t&15)*4;
  #pragma unroll
  for (int i=0;i<4;++i){
    int r = lr + i*16;
    float4 v = *(const float4*)(x + (size_t)(n0+r)*1024 + c0 + lc4);
    sF[r][lc4+0]=v.x; sF[r][lc4+1]=v.y; sF[r][lc4+2]=v.z; sF[r][lc4+3]=v.w;
  }
  __syncthreads();
  const int wr = t>>3, wc8 = (t&7)*8;
  #pragma unroll
  for (int i=0;i<2;++i){
    int r = wr + i*32;
    union{ bf16 h[8]; uint4 u; } p;
    #pragma unroll
    for (int j=0;j<8;++j) p.h[j] = (bf16)sF[r][wc8+j];
    *(uint4*)(xb + (size_t)(n0+r)*1024 + c0 + wc8) = p.u;
  }
  #pragma unroll
  for (int i=0;i<2;++i){
    int c = wr + i*32;
    union{ bf16 h[8]; uint4 u; } p;
    #pragma unroll
    for (int j=0;j<8;++j) p.h[j] = (bf16)sF[wc8+j][c];
    *(uint4*)(xT + (size_t)(c0+c)*4096 + n0 + wc8) = p.u;
  }
}

// ---------- transpose + cast: WT[c][r] = W[r][c] ----------
__global__ __launch_bounds__(256) void k_transpose(const float* __restrict__ W, bf16* __restrict__ WT,
                                                   int R, int Ccols){
  __shared__ float tile[32][33];
  int bc = blockIdx.x*32, br = blockIdx.y*32;
  int lc = threadIdx.x & 31, lr = threadIdx.x >> 5;
  #pragma unroll
  for (int i=0;i<4;i++){
    int r = lr + i*8;
    tile[r][lc] = W[(size_t)(br+r)*Ccols + bc + lc];
  }
  __syncthreads();
  #pragma unroll
  for (int i=0;i<4;i++){
    int r = lr + i*8;
    WT[(size_t)(bc+r)*R + br + lc] = (bf16)tile[lc][r];
  }
}

// =====================================================================
// 128x128-tile bf16 GEMM (r1 structure), batched via z.
// =====================================================================
template<int EPI>
__global__ __launch_bounds__(256) void k_gemm128(
    const bf16* __restrict__ A, const bf16* __restrict__ BT, bf16* __restrict__ C,
    int N, int K, int lda, int ldb,
    size_t As, size_t Bs, size_t Cs,
    const float* __restrict__ bias, const bf16* __restrict__ resid, size_t Rs)
{
  A += blockIdx.z*As; BT += blockIdx.z*Bs; C += blockIdx.z*Cs;
  if (EPI==1) resid += blockIdx.z*Rs;
  __shared__ __align__(16) bf16 sA[128*64];
  __shared__ __align__(16) bf16 sB[128*64];
  const int t = threadIdx.x, w = t>>6, l = t&63;
  const int bm = blockIdx.y*128, bn = blockIdx.x*128;
  const int wr = (w>>1)*64, wc = (w&1)*64;
  f32x4 acc[4][4] = {};
  const int srow = l>>3;
  const int scol = ((l&7) ^ (l>>3))*8;
  const int nk = K>>6;
  for (int kt=0; kt<nk; ++kt) {
    const int k0 = kt*64;
    #pragma unroll
    for (int i=0;i<4;++i){
      int c = w*4+i;
      int row = c*8 + srow;
      gload_lds16(A  + (size_t)(bm+row)*lda + k0 + scol, (char*)sA + c*1024);
      gload_lds16(BT + (size_t)(bn+row)*ldb + k0 + scol, (char*)sB + c*1024);
    }
    __syncthreads();
    #pragma unroll
    for (int kk=0; kk<64; kk+=32) {
      bf16x8 af[4], bfr[4];
      const int xr = ((kk + 8*(l>>4))*2) ^ ((l&7)<<4);
      #pragma unroll
      for (int mf=0;mf<4;++mf){
        int row = wr + mf*16 + (l&15);
        af[mf] = *(const bf16x8*)((const char*)sA + row*128 + xr);
      }
      #pragma unroll
      for (int nf=0;nf<4;++nf){
        int row = wc + nf*16 + (l&15);
        bfr[nf] = *(const bf16x8*)((const char*)sB + row*128 + xr);
      }
      #pragma unroll
      for (int mf=0;mf<4;++mf)
        #pragma unroll
        for (int nf=0;nf<4;++nf)
          acc[mf][nf] = __builtin_amdgcn_mfma_f32_16x16x32_bf16(af[mf], bfr[nf], acc[mf][nf], 0,0,0);
    }
    __syncthreads();
  }
  #pragma unroll
  for (int mf=0;mf<4;++mf)
    #pragma unroll
    for (int nf=0;nf<4;++nf)
      #pragma unroll
      for (int r=0;r<4;++r){
        int row = bm + wr + mf*16 + (l>>4)*4 + r;
        int col = bn + wc + nf*16 + (l&15);
        float v = acc[mf][nf][r];
        if (EPI==1) v += bias[col] + (float)resid[(size_t)row*N + col];
        C[(size_t)row*N + col] = (bf16)v;
      }
}

// =====================================================================
// 256x256-tile pipelined GEMM (r3 structure), fused epilogue:
// C = bf16(A*BT^T + bias + resid), resid bf16, batched via z.
// =====================================================================
__global__ __launch_bounds__(512, 2) void k_gemm256(
    const bf16* __restrict__ A, const bf16* __restrict__ BT, bf16* __restrict__ C,
    int N, int K,
    const float* __restrict__ bias, const bf16* __restrict__ resid,
    size_t As, size_t Bs, size_t Cs, size_t Rs)
{
  A += blockIdx.z*As; BT += blockIdx.z*Bs; C += blockIdx.z*Cs; resid += blockIdx.z*Rs;
  __shared__ __align__(16) bf16 lds[2][2][256*64];
  bf16* bA0 = &lds[0][0][0]; bf16* bB0 = &lds[0][1][0];
  bf16* bA1 = &lds[1][0][0]; bf16* bB1 = &lds[1][1][0];

  const int t = threadIdx.x, w = t>>6, l = t&63;
  const int wm = w>>2, wn = w&3;

  const int nwg = gridDim.x * gridDim.y;
  const int orig = blockIdx.y * gridDim.x + blockIdx.x;
  const int q = nwg >> 3, r = nwg & 7;
  const int xcd = orig & 7, loc = orig >> 3;
  const int swz = (xcd < r ? xcd*(q+1) : r*(q+1) + (xcd-r)*q) + loc;
  const int bx = swz % gridDim.x, by = swz / gridDim.x;
  const int bm = by*256, bn = bx*256;

  const int co0 = (16*(l>>4)) ^ ((l&7)<<4);
  const int co1 = (64 + 16*(l>>4)) ^ ((l&7)<<4);

  auto stageA = [&](const bf16* G, bf16* Ldst, int j, int k0){
    int row = wm*128 + wn*32 + j*8 + (l>>3);
    int col = 8*((l&7) ^ (l>>3));
    gload_lds16(G + (size_t)(bm + row)*K + k0 + col,
                Ldst + (wm*128 + wn*32 + j*8)*64);
  };
  auto stageB = [&](const bf16* G, bf16* Ldst, int j, int k0){
    int row = j*64 + w*8 + (l>>3);
    int col = 8*((l&7) ^ (l>>3));
    gload_lds16(G + (size_t)(bn + row)*K + k0 + col,
                Ldst + (j*64 + w*8)*64);
  };

#define RD_AA(dst, qd, base) {                                                  \
    const int r0 = wm*128 + (qd)*32 + (l&15);                                   \
    dst[0][0] = *(const bf16x8*)((const char*)(base) + (r0   )*128 + co0);      \
    dst[0][1] = *(const bf16x8*)((const char*)(base) + (r0   )*128 + co1);      \
    dst[1][0] = *(const bf16x8*)((const char*)(base) + (r0+16)*128 + co0);      \
    dst[1][1] = *(const bf16x8*)((const char*)(base) + (r0+16)*128 + co1);      \
  }

#define MFMA_Q(P, AA) {                                                         \
    __builtin_amdgcn_s_setprio(1);                                              \
    _Pragma("unroll")                                                           \
    for (int kk=0;kk<2;++kk)                                                    \
      _Pragma("unroll")                                                         \
      for (int i=0;i<2;++i)                                                     \
        _Pragma("unroll")                                                       \
        for (int nf=0;nf<4;++nf)                                                \
          acc[2*(P)+i][nf] = __builtin_amdgcn_mfma_f32_16x16x32_bf16(           \
              AA[i][kk], bfr[nf][kk], acc[2*(P)+i][nf], 0,0,0);                 \
    __builtin_amdgcn_s_setprio(0);                                              \
  }

#define BAR asm volatile("s_barrier" ::: "memory")

  f32x4 acc[8][4] = {};
  const int NT = K >> 6;

  #pragma unroll
  for (int j=0;j<4;++j) stageA(A, bA0, j, 0);
  #pragma unroll
  for (int j=0;j<4;++j) stageB(BT, bB0, j, 0);
  __builtin_amdgcn_sched_barrier(0);
  if (NT > 1){
    #pragma unroll
    for (int j=0;j<4;++j) stageB(BT, bB1, j, 64);
    asm volatile("s_waitcnt vmcnt(4)" ::: "memory");
  } else {
    asm volatile("s_waitcnt vmcnt(0)" ::: "memory");
  }
  BAR;

  bf16x8 aaA[2][2], aaB[2][2];
  RD_AA(aaA, wn, bA0);

  for (int T = 0; T < NT; ++T){
    bf16* sA  = (T&1) ? bA1 : bA0;
    bf16* sB  = (T&1) ? bB1 : bB0;
    bf16* sAn = (T&1) ? bA0 : bA1;
    const int kA = (T+1)<<6, kB = (T+2)<<6;
    const bool stA = (T+1) < NT, stB = (T+2) < NT;

    bf16x8 bfr[4][2];
    const int rb = wn*64 + (l&15);
    #pragma unroll
    for (int nf=0;nf<4;++nf){
      bfr[nf][0] = *(const bf16x8*)((const char*)sB + (rb+nf*16)*128 + co0);
      bfr[nf][1] = *(const bf16x8*)((const char*)sB + (rb+nf*16)*128 + co1);
    }

    RD_AA(aaB, (wn+1)&3, sA);
    if (stA){ stageA(A, sAn, 0, kA); stageA(A, sAn, 1, kA); }
    BAR; MFMA_Q(0, aaA); BAR;

    RD_AA(aaA, (wn+2)&3, sA);
    if (stA){ stageA(A, sAn, 2, kA); stageA(A, sAn, 3, kA); }
    BAR; MFMA_Q(1, aaB); BAR;

    RD_AA(aaB, (wn+3)&3, sA);
    if (stB){ stageB(BT, sB, 0, kB); stageB(BT, sB, 1, kB); }
    BAR; MFMA_Q(2, aaA); BAR;

    if (stB){
      stageB(BT, sB, 2, kB); stageB(BT, sB, 3, kB);
      asm volatile("s_waitcnt vmcnt(4)" ::: "memory");
    } else {
      asm volatile("s_waitcnt vmcnt(0)" ::: "memory");
    }
    if (stA) RD_AA(aaA, wn, sAn);
    BAR; MFMA_Q(3, aaB); BAR;
  }
#undef RD_AA
#undef MFMA_Q
#undef BAR

  #pragma unroll
  for (int P=0; P<4; ++P){
    const int qd = (P+wn)&3;
    #pragma unroll
    for (int i=0;i<2;++i){
      #pragma unroll
      for (int nf=0; nf<4; ++nf){
        #pragma unroll
        for (int r2=0; r2<4; ++r2){
          int row = bm + wm*128 + qd*32 + i*16 + (l>>4)*4 + r2;
          int col = bn + wn*64 + nf*16 + (l&15);
          float v = acc[2*P+i][nf][r2] + bias[col] + (float)resid[(size_t)row*N + col];
          C[(size_t)row*N + col] = (bf16)v;
        }
      }
    }
  }
}

// =====================================================================
// Gram via gemm256 pipeline: 256^2 upper-tri tiles (10/batch), split-K-3
// (K-tile slices 22/21/21 of 64 total), fp32 partials. Grid (10,8,3),
// 512 thr -> 240 blocks = 1/CU, single round, tail-free.
// =====================================================================
__global__ __launch_bounds__(512, 2) void k_gram256(const bf16* __restrict__ xT, float* __restrict__ Gp){
  const int t10o = blockIdx.x, b = blockIdx.y, z = blockIdx.z;
  int td = t10o, i = 0;
  while (td >= 4 - i){ td -= 4 - i; ++i; }
  const int j = i + td;                     // i <= j, 4x4 grid
  const int kofs = (z==0) ? 0 : (z==1 ? 22 : 43);
  const int NT   = (z==0) ? 22 : 21;
  const bf16* A = xT + (size_t)b*4194304;
  float* P = Gp + ((size_t)(z*80 + b*10 + t10o))*65536;
  const int bm = i*256, bn = j*256;

  __shared__ __align__(16) bf16 lds[2][2][256*64];
  bf16* bA0 = &lds[0][0][0]; bf16* bB0 = &lds[0][1][0];
  bf16* bA1 = &lds[1][0][0]; bf16* bB1 = &lds[1][1][0];

  const int t = threadIdx.x, w = t>>6, l = t&63;
  const int wm = w>>2, wn = w&3;

  const int co0 = (16*(l>>4)) ^ ((l&7)<<4);
  const int co1 = (64 + 16*(l>>4)) ^ ((l&7)<<4);

  auto stageA = [&](bf16* Ldst, int jj, int k0){
    int row = wm*128 + wn*32 + jj*8 + (l>>3);
    int col = 8*((l&7) ^ (l>>3));
    gload_lds16(A + (size_t)(bm + row)*4096 + k0 + col,
                Ldst + (wm*128 + wn*32 + jj*8)*64);
  };
  auto stageB = [&](bf16* Ldst, int jj, int k0){
    int row = jj*64 + w*8 + (l>>3);
    int col = 8*((l&7) ^ (l>>3));
    gload_lds16(A + (size_t)(bn + row)*4096 + k0 + col,
                Ldst + (jj*64 + w*8)*64);
  };

#define RD_AA(dst, qd, base) {                                                  \
    const int r0 = wm*128 + (qd)*32 + (l&15);                                   \
    dst[0][0] = *(const bf16x8*)((const char*)(base) + (r0   )*128 + co0);      \
    dst[0][1] = *(const bf16x8*)((const char*)(base) + (r0   )*128 + co1);      \
    dst[1][0] = *(const bf16x8*)((const char*)(base) + (r0+16)*128 + co0);      \
    dst[1][1] = *(const bf16x8*)((const char*)(base) + (r0+16)*128 + co1);      \
  }

#define MFMA_Q(P, AA) {                                                         \
    __builtin_amdgcn_s_setprio(1);                                              \
    _Pragma("unroll")                                                           \
    for (int kk=0;kk<2;++kk)                                                    \
      _Pragma("unroll")                                                         \
      for (int i2=0;i2<2;++i2)                                                  \
        _Pragma("unroll")                                                       \
        for (int nf=0;nf<4;++nf)                                                \
          acc[2*(P)+i2][nf] = __builtin_amdgcn_mfma_f32_16x16x32_bf16(          \
              AA[i2][kk], bfr[nf][kk], acc[2*(P)+i2][nf], 0,0,0);               \
    __builtin_amdgcn_s_setprio(0);                                              \
  }

#define BAR asm volatile("s_barrier" ::: "memory")

  f32x4 acc[8][4] = {};
  const int k0base = kofs*64;

  #pragma unroll
  for (int jj=0;jj<4;++jj) stageA(bA0, jj, k0base);
  #pragma unroll
  for (int jj=0;jj<4;++jj) stageB(bB0, jj, k0base);
  __builtin_amdgcn_sched_barrier(0);
  {
    #pragma unroll
    for (int jj=0;jj<4;++jj) stageB(bB1, jj, k0base + 64);
    asm volatile("s_waitcnt vmcnt(4)" ::: "memory");
  }
  BAR;

  bf16x8 aaA[2][2], aaB[2][2];
  RD_AA(aaA, wn, bA0);

  for (int T = 0; T < NT; ++T){
    bf16* sA  = (T&1) ? bA1 : bA0;
    bf16* sB  = (T&1) ? bB1 : bB0;
    bf16* sAn = (T&1) ? bA0 : bA1;
    const int kA = k0base + ((T+1)<<6), kB = k0base + ((T+2)<<6);
    const bool stA = (T+1) < NT, stB = (T+2) < NT;

    bf16x8 bfr[4][2];
    const int rb = wn*64 + (l&15);
    #pragma unroll
    for (int nf=0;nf<4;++nf){
      bfr[nf][0] = *(const bf16x8*)((const char*)sB + (rb+nf*16)*128 + co0);
      bfr[nf][1] = *(const bf16x8*)((const char*)sB + (rb+nf*16)*128 + co1);
    }

    RD_AA(aaB, (wn+1)&3, sA);
    if (stA){ stageA(sAn, 0, kA); stageA(sAn, 1, kA); }
    BAR; MFMA_Q(0, aaA); BAR;

    RD_AA(aaA, (wn+2)&3, sA);
    if (stA){ stageA(sAn, 2, kA); stageA(sAn, 3, kA); }
    BAR; MFMA_Q(1, aaB); BAR;

    RD_AA(aaB, (wn+3)&3, sA);
    if (stB){ stageB(sB, 0, kB); stageB(sB, 1, kB); }
    BAR; MFMA_Q(2, aaA); BAR;

    if (stB){
      stageB(sB, 2, kB); stageB(sB, 3, kB);
      asm volatile("s_waitcnt vmcnt(4)" ::: "memory");
    } else {
      asm volatile("s_waitcnt vmcnt(0)" ::: "memory");
    }
    if (stA) RD_AA(aaA, wn, sAn);
    BAR; MFMA_Q(3, aaB); BAR;
  }
#undef RD_AA
#undef MFMA_Q
#undef BAR

  #pragma unroll
  for (int Pq=0; Pq<4; ++Pq){
    const int qd = (Pq+wn)&3;
    #pragma unroll
    for (int i2=0;i2<2;++i2){
      #pragma unroll
      for (int nf=0; nf<4; ++nf){
        #pragma unroll
        for (int r2=0; r2<4; ++r2){
          int row = wm*128 + qd*32 + i2*16 + (l>>4)*4 + r2;
          int col = wn*64 + nf*16 + (l&15);
          P[row*256 + col] = acc[2*Pq+i2][nf][r2];
        }
      }
    }
  }
}

// =====================================================================
// Gram reduce: per-128^2-quadrant, sum 3 fp32 partials -> bf16 + mirror.
// Grid (10,8,4): q = (qr<<1)|qc quadrant of the 256^2 tile.
// =====================================================================
__global__ __launch_bounds__(256) void k_gramred256(const float* __restrict__ Gp, bf16* __restrict__ Gram){
  const int t10o = blockIdx.x, b = blockIdx.y, q = blockIdx.z;
  const int qr = q>>1, qc = q&1;
  int td = t10o, i = 0;
  while (td >= 4 - i){ td -= 4 - i; ++i; }
  const int j = i + td;
  const float* P0 = Gp + ((size_t)(b*10 + t10o))*65536 + qr*128*256 + qc*128;
  const float* P1 = P0 + (size_t)80*65536;
  const float* P2 = P1 + (size_t)80*65536;
  bf16* C = Gram + (size_t)b*1048576;
  const int bm = i*256 + qr*128, bn = j*256 + qc*128;
  const bool domirror = !(i==j && qr==qc);
  __shared__ float sT[128][129];
  const int t = threadIdx.x;
  const int rr = t>>4, cc = (t&15)*8;
  #pragma unroll
  for (int ch=0; ch<8; ++ch){
    const int row = ch*16 + rr;
    const int idx = row*256 + cc;
    float4 a0 = *(const float4*)(P0+idx), a1 = *(const float4*)(P0+idx+4);
    float4 b0 = *(const float4*)(P1+idx), b1 = *(const float4*)(P1+idx+4);
    float4 c0 = *(const float4*)(P2+idx), c1 = *(const float4*)(P2+idx+4);
    float s[8] = {a0.x+b0.x+c0.x, a0.y+b0.y+c0.y, a0.z+b0.z+c0.z, a0.w+b0.w+c0.w,
                  a1.x+b1.x+c1.x, a1.y+b1.y+c1.y, a1.z+b1.z+c1.z, a1.w+b1.w+c1.w};
    union{ bf16 h[8]; uint4 u; } p;
    #pragma unroll
    for (int k=0;k<8;++k) p.h[k] = (bf16)s[k];
    *(uint4*)(C + (size_t)(bm+row)*1024 + bn + cc) = p.u;
    if (domirror){
      #pragma unroll
      for (int k=0;k<8;++k) sT[row][cc+k] = s[k];
    }
  }
  if (!domirror) return;
  __syncthreads();
  #pragma unroll
  for (int ch=0; ch<8; ++ch){
    const int c = ch*16 + rr;
    union{ bf16 h[8]; uint4 u; } p;
    #pragma unroll
    for (int k=0;k<8;++k) p.h[k] = (bf16)sT[cc+k][c];
    *(uint4*)(C + (size_t)(bn+c)*1024 + bm + cc) = p.u;
  }
}

// ---------- fused S = scale * T2_g @ Wv_g^T + row softmax -> Aatt[bg][64][64] ----------
__global__ __launch_bounds__(256) void k_sgemm64(const bf16* __restrict__ T2, const bf16* __restrict__ WqkvT,
                                                 bf16* __restrict__ Aatt){
  const int bg = blockIdx.x, b = bg>>4, g = bg&15;
  const bf16* Arows = T2 + (size_t)b*1048576 + (size_t)(g*64)*1024;
  const bf16* Brows = WqkvT + (size_t)(2048 + g*64)*1024;
  __shared__ __align__(16) bf16 sA[64*64];
  __shared__ __align__(16) bf16 sB[64*64];
  const int t = threadIdx.x, w = t>>6, l = t&63;
  const int srow = l>>3, scol = ((l&7)^(l>>3))*8;
  f32x4 acc[4] = {};
  for (int kt=0; kt<16; ++kt){
    const int k0 = kt*64;
    gload_lds16(Arows + (size_t)(w*8+srow)*1024 + k0 + scol,      sA + (w*8)*64);
    gload_lds16(Arows + (size_t)(32+w*8+srow)*1024 + k0 + scol,   sA + (32+w*8)*64);
    gload_lds16(Brows + (size_t)(w*8+srow)*1024 + k0 + scol,      sB + (w*8)*64);
    gload_lds16(Brows + (size_t)(32+w*8+srow)*1024 + k0 + scol,   sB + (32+w*8)*64);
    __syncthreads();
    #pragma unroll
    for (int kk=0; kk<64; kk+=32){
      const int xr = ((kk + 8*(l>>4))*2) ^ ((l&7)<<4);
      bf16x8 af = *(const bf16x8*)((const char*)sA + (w*16+(l&15))*128 + xr);
      #pragma unroll
      for (int nf=0; nf<4; ++nf){
        bf16x8 bfv = *(const bf16x8*)((const char*)sB + (nf*16+(l&15))*128 + xr);
        acc[nf] = __builtin_amdgcn_mfma_f32_16x16x32_bf16(af, bfv, acc[nf], 0,0,0);
      }
    }
    __syncthreads();
  }
  #pragma unroll
  for (int reg=0; reg<4; ++reg){
    float m = -3.4e38f;
    #pragma unroll
    for (int nf=0; nf<4; ++nf) m = fmaxf(m, acc[nf][reg]);
    m = fmaxf(m, __shfl_xor(m,1)); m = fmaxf(m, __shfl_xor(m,2));
    m = fmaxf(m, __shfl_xor(m,4)); m = fmaxf(m, __shfl_xor(m,8));
    float e[4]; float s = 0.f;
    #pragma unroll
    for (int nf=0; nf<4; ++nf){ e[nf] = __expf((acc[nf][reg]-m)*0.125f); s += e[nf]; }
    s += __shfl_xor(s,1); s += __shfl_xor(s,2); s += __shfl_xor(s,4); s += __shfl_xor(s,8);
    const float inv = 1.0f/s;
    const int row = w*16 + (l>>4)*4 + reg;
    #pragma unroll
    for (int nf=0; nf<4; ++nf)
      Aatt[(size_t)bg*4096 + row*64 + nf*16 + (l&15)] = (bf16)(e[nf]*inv);
  }
}

// ---------- U[c][g*64+d] = sum_e Wq[c][g*64+e] * Aatt_bg[d][e] ----------
__global__ __launch_bounds__(256) void k_applyW(const bf16* __restrict__ Wqkvb, const bf16* __restrict__ Aatt,
                                                bf16* __restrict__ U){
  const int bg = blockIdx.y, b = bg>>4, g = bg&15;
  const int m0 = blockIdx.x*128;
  __shared__ __align__(16) bf16 Pl[64][72];
  const int t = threadIdx.x, w = t>>6, l = t&63;
  for (int idx=t; idx<1024; idx+=256){
    int r2 = idx>>4, c4 = (idx&15)*4;
    *(uint2*)&Pl[r2][c4] = *(const uint2*)&Aatt[(size_t)bg*4096 + r2*64 + c4];
  }
  __syncthreads();
  f32x4 acc[2][4] = {};
  const bf16* Ab = Wqkvb + (size_t)(m0 + w*32)*3072 + g*64;
  #pragma unroll
  for (int kk=0; kk<64; kk+=32){
    bf16x8 af[2], pf[4];
    #pragma unroll
    for (int mf=0;mf<2;++mf)
      af[mf] = *(const bf16x8*)(Ab + (size_t)(mf*16 + (l&15))*3072 + kk + 8*(l>>4));
    #pragma unroll
    for (int nf=0;nf<4;++nf)
      pf[nf] = *(const bf16x8*)&Pl[nf*16 + (l&15)][kk + 8*(l>>4)];
    #pragma unroll
    for (int mf=0;mf<2;++mf)
      #pragma unroll
      for (int nf=0;nf<4;++nf)
        acc[mf][nf] = __builtin_amdgcn_mfma_f32_16x16x32_bf16(af[mf], pf[nf], acc[mf][nf], 0,0,0);
  }
  #pragma unroll
  for (int mf=0;mf<2;++mf)
    #pragma unroll
    for (int nf=0;nf<4;++nf)
      #pragma unroll
      for (int r=0;r<4;++r){
        int rowc = m0 + w*32 + mf*16 + (l>>4)*4 + r;
        int col = g*64 + nf*16 + (l&15);
        U[(size_t)b*1048576 + (size_t)rowc*1024 + col] = (bf16)acc[mf][nf][r];
      }
}

// ---------- LayerNorm: wave per row of 1024 ----------
__global__ __launch_bounds__(256) void k_ln(const bf16* __restrict__ h, const float* __restrict__ gamma,
                                            const float* __restrict__ beta, float* __restrict__ y){
  const int w = threadIdx.x>>6, l = threadIdx.x&63;
  const size_t row = (size_t)blockIdx.x*4 + w;
  const bf16* hr = h + row*1024 + l*16;
  uint4 p0 = *(const uint4*)hr;
  uint4 p1 = *(const uint4*)(hr+8);
  float v[16];
  const uint32_t* pw = (const uint32_t*)&p0;
  #pragma unroll
  for (int i=0;i<4;++i){ v[2*i] = bits2f(pw[i]<<16); v[2*i+1] = bits2f(pw[i]&0xffff0000u); }
  const uint32_t* pw1 = (const uint32_t*)&p1;
  #pragma unroll
  for (int i=0;i<4;++i){ v[8+2*i] = bits2f(pw1[i]<<16); v[8+2*i+1] = bits2f(pw1[i]&0xffff0000u); }
  float s=0.f, s2=0.f;
  #pragma unroll
  for (int i=0;i<16;++i){ s+=v[i]; s2+=v[i]*v[i]; }
  #pragma unroll
  for (int off=1; off<64; off<<=1){ s += __shfl_xor(s,off); s2 += __shfl_xor(s2,off); }
  float mu = s*(1.0f/1024.0f);
  float var = s2*(1.0f/1024.0f) - mu*mu;
  float rinv = rsqrtf(var + 1e-5f);
  const float* gp = gamma + l*16; const float* bp = beta + l*16;
  float o[16];
  #pragma unroll
  for (int i=0;i<16;++i) o[i] = gp[i]*(v[i]-mu)*rinv + bp[i];
  float* yr = y + row*1024 + l*16;
  #pragma unroll
  for (int i=0;i<4;++i) ((float4*)yr)[i] = *(float4*)&o[4*i];
}

extern "C" void kernel_launch(void* const* d_in, const int* in_sizes, int n_in,
                              void* d_out, int out_size, void* d_ws, size_t ws_size,
                              hipStream_t stream){
  const float* x     = (const float*)d_in[0];
  const float* Wqkv  = (const float*)d_in[1];
  const float* Wproj = (const float*)d_in[2];
  const float* bproj = (const float*)d_in[3];
  const float* gamma = (const float*)d_in[4];
  const float* beta  = (const float*)d_in[5];
  float* y = (float*)d_out;

  char* ws = (char*)d_ws;
  size_t off = 0;
  auto alloc = [&](size_t bytes)->void*{ void* p = ws + off; off += (bytes + 255) & ~(size_t)255; return p; };
  bf16*  xb     = (bf16*) alloc((size_t)32768*1024*2);   // 67.1 MB
  bf16*  xT     = (bf16*) alloc((size_t)8*1024*4096*2);  // 67.1 MB (reused as h)
  bf16*  Wqkvb  = (bf16*) alloc((size_t)1024*3072*2);
  bf16*  WqkvT  = (bf16*) alloc((size_t)3072*1024*2);
  bf16*  WprojT = (bf16*) alloc((size_t)1024*1024*2);
  bf16*  Gram   = (bf16*) alloc((size_t)8*1024*1024*2);  // 16.8 MB
  bf16*  T2     = (bf16*) alloc((size_t)8*1024*1024*2);
  bf16*  Aatt   = (bf16*) alloc((size_t)128*64*64*2);
  bf16*  U      = (bf16*) alloc((size_t)8*1024*1024*2);
  bf16*  WeffT  = (bf16*) alloc((size_t)8*1024*1024*2);
  float* Gp     = (float*)alloc((size_t)3*80*65536*4);   // 62.9 MB fp32 partials
  bf16*  h      = xT;   // xT dead after Gram

  const size_t MB1 = 1048576;
  const size_t MB4 = (size_t)4096*1024;

  k_castT<<<dim3(16,64,8),256,0,stream>>>(x, xb, xT);
  k_cast<<<1536,256,0,stream>>>(Wqkv, Wqkvb, 3145728);
  k_transpose<<<dim3(96,32),256,0,stream>>>(Wqkv, WqkvT, 1024, 3072);
  k_transpose<<<dim3(32,32),256,0,stream>>>(Wproj, WprojT, 1024, 1024);
  // Gram_b = xT_b @ xT_b^T (256^2 upper tiles, gemm256 pipeline, split-K 3)
  k_gram256<<<dim3(10,8,3),512,0,stream>>>(xT, Gp);
  k_gramred256<<<dim3(10,8,4),256,0,stream>>>(Gp, Gram);
  // T2_b = Wk^T @ Gram_b  [1024x1024], K=1024  (Gram symmetric)
  k_gemm128<0><<<dim3(8,8,8),256,0,stream>>>(WqkvT + (size_t)1024*1024, Gram, T2, 1024, 1024, 1024, 1024,
                                             0, MB1, MB1, nullptr, nullptr, 0);
  // S + softmax -> Aatt (fused)
  k_sgemm64<<<128,256,0,stream>>>(T2, WqkvT, Aatt);
  // U_b[:, g-block] = Wq_g @ Aatt_bg^T
  k_applyW<<<dim3(8,128),256,0,stream>>>(Wqkvb, Aatt, U);
  // WeffT_b = WprojT @ U_b^T  [1024x1024], K=1024
  k_gemm128<0><<<dim3(8,8,8),256,0,stream>>>(WprojT, U, WeffT, 1024, 1024, 1024, 1024,
                                             0, MB1, MB1, nullptr, nullptr, 0);
  // h_b = xb_b @ WeffT_b^T + bproj + xb_b   [4096x1024] per batch
  k_gemm256<<<dim3(4,16,8),512,0,stream>>>(xb, WeffT, h, 1024, 1024, bproj, xb,
                                           MB4, MB1, MB4, MB4);
  k_ln<<<8192,256,0,stream>>>(h, gamma, beta, y);
}

// Round 13
// 326.081 us; speedup vs baseline: 1.1415x; 1.0148x over previous
//
#include <hip/hip_runtime.h>
#include <cstdint>

typedef __bf16 bf16;
typedef __bf16 bf16x8 __attribute__((ext_vector_type(8)));
typedef float f32x4 __attribute__((ext_vector_type(4)));

#define DEVI __device__ __forceinline__

DEVI float bits2f(uint32_t u){ union{uint32_t u;float f;}x; x.u=u; return x.f; }

DEVI void gload_lds16(const void* g, void* l){
  __builtin_amdgcn_global_load_lds(
    (const __attribute__((address_space(1))) uint32_t*)g,
    (__attribute__((address_space(3))) uint32_t*)l, 16, 0, 0);
}

// ---------- cast fp32 -> bf16, 8 elems/thread ----------
__global__ __launch_bounds__(256) void k_cast(const float* __restrict__ x, bf16* __restrict__ o, int n){
  int i = (blockIdx.x*256 + threadIdx.x)*8;
  if (i >= n) return;
  float4 a = *(const float4*)(x+i);
  float4 b = *(const float4*)(x+i+4);
  union { bf16 h[8]; uint4 u; } r;
  r.h[0]=(bf16)a.x; r.h[1]=(bf16)a.y; r.h[2]=(bf16)a.z; r.h[3]=(bf16)a.w;
  r.h[4]=(bf16)b.x; r.h[5]=(bf16)b.y; r.h[6]=(bf16)b.z; r.h[7]=(bf16)b.w;
  *(uint4*)(o+i) = r.u;
}

// ---------- fused: read x fp32 once -> xb (bf16) + xT (bf16 transposed) ----------
__global__ __launch_bounds__(256) void k_castT(const float* __restrict__ x, bf16* __restrict__ xb,
                                               bf16* __restrict__ xT){
  const int b = blockIdx.z;
  x  += (size_t)b*4194304; xb += (size_t)b*4194304; xT += (size_t)b*4194304;
  const int n0 = blockIdx.y*64, c0 = blockIdx.x*64;
  __shared__ float sF[64][65];
  const int t = threadIdx.x;
  const int lr = t>>4, lc4 = (t&15)*4;
  #pragma unroll
  for (int i=0;i<4;++i){
    int r = lr + i*16;
    float4 v = *(const float4*)(x + (size_t)(n0+r)*1024 + c0 + lc4);
    sF[r][lc4+0]=v.x; sF[r][lc4+1]=v.y; sF[r][lc4+2]=v.z; sF[r][lc4+3]=v.w;
  }
  __syncthreads();
  const int wr = t>>3, wc8 = (t&7)*8;
  #pragma unroll
  for (int i=0;i<2;++i){
    int r = wr + i*32;
    union{ bf16 h[8]; uint4 u; } p;
    #pragma unroll
    for (int j=0;j<8;++j) p.h[j] = (bf16)sF[r][wc8+j];
    *(uint4*)(xb + (size_t)(n0+r)*1024 + c0 + wc8) = p.u;
  }
  #pragma unroll
  for (int i=0;i<2;++i){
    int c = wr + i*32;
    union{ bf16 h[8]; uint4 u; } p;
    #pragma unroll
    for (int j=0;j<8;++j) p.h[j] = (bf16)sF[wc8+j][c];
    *(uint4*)(xT + (size_t)(c0+c)*4096 + n0 + wc8) = p.u;
  }
}

// ---------- transpose + cast: WT[c][r] = W[r][c] ----------
__global__ __launch_bounds__(256) void k_transpose(const float* __restrict__ W, bf16* __restrict__ WT,
                                                   int R, int Ccols){
  __shared__ float tile[32][33];
  int bc = blockIdx.x*32, br = blockIdx.y*32;
  int lc = threadIdx.x & 31, lr = threadIdx.x >> 5;
  #pragma unroll
  for (int i=0;i<4;i++){
    int r = lr + i*8;
    tile[r][lc] = W[(size_t)(br+r)*Ccols + bc + lc];
  }
  __syncthreads();
  #pragma unroll
  for (int i=0;i<4;i++){
    int r = lr + i*8;
    WT[(size_t)(bc+r)*R + br + lc] = (bf16)tile[lc][r];
  }
}

// =====================================================================
// 128x128-tile bf16 GEMM (r1 structure), batched via z.
// =====================================================================
template<int EPI>
__global__ __launch_bounds__(256) void k_gemm128(
    const bf16* __restrict__ A, const bf16* __restrict__ BT, bf16* __restrict__ C,
    int N, int K, int lda, int ldb,
    size_t As, size_t Bs, size_t Cs,
    const float* __restrict__ bias, const bf16* __restrict__ resid, size_t Rs)
{
  A += blockIdx.z*As; BT += blockIdx.z*Bs; C += blockIdx.z*Cs;
  if (EPI==1) resid += blockIdx.z*Rs;
  __shared__ __align__(16) bf16 sA[128*64];
  __shared__ __align__(16) bf16 sB[128*64];
  const int t = threadIdx.x, w = t>>6, l = t&63;
  const int bm = blockIdx.y*128, bn = blockIdx.x*128;
  const int wr = (w>>1)*64, wc = (w&1)*64;
  f32x4 acc[4][4] = {};
  const int srow = l>>3;
  const int scol = ((l&7) ^ (l>>3))*8;
  const int nk = K>>6;
  for (int kt=0; kt<nk; ++kt) {
    const int k0 = kt*64;
    #pragma unroll
    for (int i=0;i<4;++i){
      int c = w*4+i;
      int row = c*8 + srow;
      gload_lds16(A  + (size_t)(bm+row)*lda + k0 + scol, (char*)sA + c*1024);
      gload_lds16(BT + (size_t)(bn+row)*ldb + k0 + scol, (char*)sB + c*1024);
    }
    __syncthreads();
    #pragma unroll
    for (int kk=0; kk<64; kk+=32) {
      bf16x8 af[4], bfr[4];
      const int xr = ((kk + 8*(l>>4))*2) ^ ((l&7)<<4);
      #pragma unroll
      for (int mf=0;mf<4;++mf){
        int row = wr + mf*16 + (l&15);
        af[mf] = *(const bf16x8*)((const char*)sA + row*128 + xr);
      }
      #pragma unroll
      for (int nf=0;nf<4;++nf){
        int row = wc + nf*16 + (l&15);
        bfr[nf] = *(const bf16x8*)((const char*)sB + row*128 + xr);
      }
      #pragma unroll
      for (int mf=0;mf<4;++mf)
        #pragma unroll
        for (int nf=0;nf<4;++nf)
          acc[mf][nf] = __builtin_amdgcn_mfma_f32_16x16x32_bf16(af[mf], bfr[nf], acc[mf][nf], 0,0,0);
    }
    __syncthreads();
  }
  #pragma unroll
  for (int mf=0;mf<4;++mf)
    #pragma unroll
    for (int nf=0;nf<4;++nf)
      #pragma unroll
      for (int r=0;r<4;++r){
        int row = bm + wr + mf*16 + (l>>4)*4 + r;
        int col = bn + wc + nf*16 + (l&15);
        float v = acc[mf][nf][r];
        if (EPI==1) v += bias[col] + (float)resid[(size_t)row*N + col];
        C[(size_t)row*N + col] = (bf16)v;
      }
}

// =====================================================================
// 256x256-tile pipelined GEMM (r3 structure) specialized for h:
// grid MUST be (4,16,8). By-major XCD chunking (A-panel co-location),
// fused epilogue C = bf16(A*BT^T + bias + resid) with resid staged
// coalesced through LDS after the K-loop.
// =====================================================================
__global__ __launch_bounds__(512, 2) void k_gemm256(
    const bf16* __restrict__ A, const bf16* __restrict__ BT, bf16* __restrict__ C,
    int N, int K,
    const float* __restrict__ bias, const bf16* __restrict__ resid,
    size_t As, size_t Bs, size_t Cs, size_t Rs)
{
  __shared__ __align__(16) bf16 lds[2][2][256*64];
  bf16* bA0 = &lds[0][0][0]; bf16* bB0 = &lds[0][1][0];
  bf16* bA1 = &lds[1][0][0]; bf16* bB1 = &lds[1][1][0];

  const int t = threadIdx.x, w = t>>6, l = t&63;
  const int wm = w>>2, wn = w&3;

  // by-major XCD chunking: blocks sharing an A-panel (same z,by; bx=0..3)
  // get the same d&7 -> same XCD under round-robin. Bijective for 512 blocks.
  const int d = (blockIdx.z*gridDim.y + blockIdx.y)*gridDim.x + blockIdx.x;
  const int gch = ((d>>5)<<3) | (d&7);       // group z*16+by in [0,128)
  const int bxn = (d>>3)&3;
  const int zn  = gch>>4, byn = gch&15;
  const int bm = byn*256, bn = bxn*256;
  A += (size_t)zn*As; BT += (size_t)zn*Bs; C += (size_t)zn*Cs; resid += (size_t)zn*Rs;

  const int co0 = (16*(l>>4)) ^ ((l&7)<<4);
  const int co1 = (64 + 16*(l>>4)) ^ ((l&7)<<4);

  auto stageA = [&](const bf16* G, bf16* Ldst, int j, int k0){
    int row = wm*128 + wn*32 + j*8 + (l>>3);
    int col = 8*((l&7) ^ (l>>3));
    gload_lds16(G + (size_t)(bm + row)*K + k0 + col,
                Ldst + (wm*128 + wn*32 + j*8)*64);
  };
  auto stageB = [&](const bf16* G, bf16* Ldst, int j, int k0){
    int row = j*64 + w*8 + (l>>3);
    int col = 8*((l&7) ^ (l>>3));
    gload_lds16(G + (size_t)(bn + row)*K + k0 + col,
                Ldst + (j*64 + w*8)*64);
  };

#define RD_AA(dst, qd, base) {                                                  \
    const int r0 = wm*128 + (qd)*32 + (l&15);                                   \
    dst[0][0] = *(const bf16x8*)((const char*)(base) + (r0   )*128 + co0);      \
    dst[0][1] = *(const bf16x8*)((const char*)(base) + (r0   )*128 + co1);      \
    dst[1][0] = *(const bf16x8*)((const char*)(base) + (r0+16)*128 + co0);      \
    dst[1][1] = *(const bf16x8*)((const char*)(base) + (r0+16)*128 + co1);      \
  }

#define MFMA_Q(P, AA) {                                                         \
    __builtin_amdgcn_s_setprio(1);                                              \
    _Pragma("unroll")                                                           \
    for (int kk=0;kk<2;++kk)                                                    \
      _Pragma("unroll")                                                         \
      for (int i=0;i<2;++i)                                                     \
        _Pragma("unroll")                                                       \
        for (int nf=0;nf<4;++nf)                                                \
          acc[2*(P)+i][nf] = __builtin_amdgcn_mfma_f32_16x16x32_bf16(           \
              AA[i][kk], bfr[nf][kk], acc[2*(P)+i][nf], 0,0,0);                 \
    __builtin_amdgcn_s_setprio(0);                                              \
  }

#define BAR asm volatile("s_barrier" ::: "memory")

  f32x4 acc[8][4] = {};
  const int NT = K >> 6;

  #pragma unroll
  for (int j=0;j<4;++j) stageA(A, bA0, j, 0);
  #pragma unroll
  for (int j=0;j<4;++j) stageB(BT, bB0, j, 0);
  __builtin_amdgcn_sched_barrier(0);
  if (NT > 1){
    #pragma unroll
    for (int j=0;j<4;++j) stageB(BT, bB1, j, 64);
    asm volatile("s_waitcnt vmcnt(4)" ::: "memory");
  } else {
    asm volatile("s_waitcnt vmcnt(0)" ::: "memory");
  }
  BAR;

  bf16x8 aaA[2][2], aaB[2][2];
  RD_AA(aaA, wn, bA0);

  for (int T = 0; T < NT; ++T){
    bf16* sA  = (T&1) ? bA1 : bA0;
    bf16* sB  = (T&1) ? bB1 : bB0;
    bf16* sAn = (T&1) ? bA0 : bA1;
    const int kA = (T+1)<<6, kB = (T+2)<<6;
    const bool stA = (T+1) < NT, stB = (T+2) < NT;

    bf16x8 bfr[4][2];
    const int rb = wn*64 + (l&15);
    #pragma unroll
    for (int nf=0;nf<4;++nf){
      bfr[nf][0] = *(const bf16x8*)((const char*)sB + (rb+nf*16)*128 + co0);
      bfr[nf][1] = *(const bf16x8*)((const char*)sB + (rb+nf*16)*128 + co1);
    }

    RD_AA(aaB, (wn+1)&3, sA);
    if (stA){ stageA(A, sAn, 0, kA); stageA(A, sAn, 1, kA); }
    BAR; MFMA_Q(0, aaA); BAR;

    RD_AA(aaA, (wn+2)&3, sA);
    if (stA){ stageA(A, sAn, 2, kA); stageA(A, sAn, 3, kA); }
    BAR; MFMA_Q(1, aaB); BAR;

    RD_AA(aaB, (wn+3)&3, sA);
    if (stB){ stageB(BT, sB, 0, kB); stageB(BT, sB, 1, kB); }
    BAR; MFMA_Q(2, aaA); BAR;

    if (stB){
      stageB(BT, sB, 2, kB); stageB(BT, sB, 3, kB);
      asm volatile("s_waitcnt vmcnt(4)" ::: "memory");
    } else {
      asm volatile("s_waitcnt vmcnt(0)" ::: "memory");
    }
    if (stA) RD_AA(aaA, wn, sAn);
    BAR; MFMA_Q(3, aaB); BAR;
  }
#undef RD_AA
#undef MFMA_Q
#undef BAR

  // ---- epilogue: stage resid tile [256][256] bf16 into LDS (coalesced,
  // 16 x global_load_lds of 8KB), then read it back per-element. ----
  {
    bf16* rbase = &lds[0][0][0];   // entire 128 KiB reused
    #pragma unroll
    for (int jj=0;jj<16;++jj){
      int row = jj*16 + w*2 + (l>>5);
      gload_lds16(resid + (size_t)(bm + row)*N + bn + (l&31)*8,
                  rbase + (jj*16 + w*2)*256);
    }
    asm volatile("s_waitcnt vmcnt(0)" ::: "memory");
    asm volatile("s_barrier" ::: "memory");
    #pragma unroll
    for (int P=0; P<4; ++P){
      const int qd = (P+wn)&3;
      #pragma unroll
      for (int i=0;i<2;++i){
        #pragma unroll
        for (int nf=0; nf<4; ++nf){
          #pragma unroll
          for (int r2=0; r2<4; ++r2){
            int lrow = wm*128 + qd*32 + i*16 + (l>>4)*4 + r2;
            int lcol = wn*64 + nf*16 + (l&15);
            float v = acc[2*P+i][nf][r2] + bias[bn+lcol] + (float)rbase[lrow*256 + lcol];
            C[(size_t)(bm+lrow)*N + bn + lcol] = (bf16)v;
          }
        }
      }
    }
  }
}

// =====================================================================
// Gram via gemm256 pipeline: 256^2 upper-tri tiles (10/batch), split-K-3
// (K-tile slices 22/21/21 of 64 total), fp32 partials. Grid (10,8,3).
// =====================================================================
__global__ __launch_bounds__(512, 2) void k_gram256(const bf16* __restrict__ xT, float* __restrict__ Gp){
  const int t10o = blockIdx.x, b = blockIdx.y, z = blockIdx.z;
  int td = t10o, i = 0;
  while (td >= 4 - i){ td -= 4 - i; ++i; }
  const int j = i + td;                     // i <= j, 4x4 grid
  const int kofs = (z==0) ? 0 : (z==1 ? 22 : 43);
  const int NT   = (z==0) ? 22 : 21;
  const bf16* A = xT + (size_t)b*4194304;
  float* P = Gp + ((size_t)(z*80 + b*10 + t10o))*65536;
  const int bm = i*256, bn = j*256;

  __shared__ __align__(16) bf16 lds[2][2][256*64];
  bf16* bA0 = &lds[0][0][0]; bf16* bB0 = &lds[0][1][0];
  bf16* bA1 = &lds[1][0][0]; bf16* bB1 = &lds[1][1][0];

  const int t = threadIdx.x, w = t>>6, l = t&63;
  const int wm = w>>2, wn = w&3;

  const int co0 = (16*(l>>4)) ^ ((l&7)<<4);
  const int co1 = (64 + 16*(l>>4)) ^ ((l&7)<<4);

  auto stageA = [&](bf16* Ldst, int jj, int k0){
    int row = wm*128 + wn*32 + jj*8 + (l>>3);
    int col = 8*((l&7) ^ (l>>3));
    gload_lds16(A + (size_t)(bm + row)*4096 + k0 + col,
                Ldst + (wm*128 + wn*32 + jj*8)*64);
  };
  auto stageB = [&](bf16* Ldst, int jj, int k0){
    int row = jj*64 + w*8 + (l>>3);
    int col = 8*((l&7) ^ (l>>3));
    gload_lds16(A + (size_t)(bn + row)*4096 + k0 + col,
                Ldst + (jj*64 + w*8)*64);
  };

#define RD_AA(dst, qd, base) {                                                  \
    const int r0 = wm*128 + (qd)*32 + (l&15);                                   \
    dst[0][0] = *(const bf16x8*)((const char*)(base) + (r0   )*128 + co0);      \
    dst[0][1] = *(const bf16x8*)((const char*)(base) + (r0   )*128 + co1);      \
    dst[1][0] = *(const bf16x8*)((const char*)(base) + (r0+16)*128 + co0);      \
    dst[1][1] = *(const bf16x8*)((const char*)(base) + (r0+16)*128 + co1);      \
  }

#define MFMA_Q(P, AA) {                                                         \
    __builtin_amdgcn_s_setprio(1);                                              \
    _Pragma("unroll")                                                           \
    for (int kk=0;kk<2;++kk)                                                    \
      _Pragma("unroll")                                                         \
      for (int i2=0;i2<2;++i2)                                                  \
        _Pragma("unroll")                                                       \
        for (int nf=0;nf<4;++nf)                                                \
          acc[2*(P)+i2][nf] = __builtin_amdgcn_mfma_f32_16x16x32_bf16(          \
              AA[i2][kk], bfr[nf][kk], acc[2*(P)+i2][nf], 0,0,0);               \
    __builtin_amdgcn_s_setprio(0);                                              \
  }

#define BAR asm volatile("s_barrier" ::: "memory")

  f32x4 acc[8][4] = {};
  const int k0base = kofs*64;

  #pragma unroll
  for (int jj=0;jj<4;++jj) stageA(bA0, jj, k0base);
  #pragma unroll
  for (int jj=0;jj<4;++jj) stageB(bB0, jj, k0base);
  __builtin_amdgcn_sched_barrier(0);
  {
    #pragma unroll
    for (int jj=0;jj<4;++jj) stageB(bB1, jj, k0base + 64);
    asm volatile("s_waitcnt vmcnt(4)" ::: "memory");
  }
  BAR;

  bf16x8 aaA[2][2], aaB[2][2];
  RD_AA(aaA, wn, bA0);

  for (int T = 0; T < NT; ++T){
    bf16* sA  = (T&1) ? bA1 : bA0;
    bf16* sB  = (T&1) ? bB1 : bB0;
    bf16* sAn = (T&1) ? bA0 : bA1;
    const int kA = k0base + ((T+1)<<6), kB = k0base + ((T+2)<<6);
    const bool stA = (T+1) < NT, stB = (T+2) < NT;

    bf16x8 bfr[4][2];
    const int rb = wn*64 + (l&15);
    #pragma unroll
    for (int nf=0;nf<4;++nf){
      bfr[nf][0] = *(const bf16x8*)((const char*)sB + (rb+nf*16)*128 + co0);
      bfr[nf][1] = *(const bf16x8*)((const char*)sB + (rb+nf*16)*128 + co1);
    }

    RD_AA(aaB, (wn+1)&3, sA);
    if (stA){ stageA(sAn, 0, kA); stageA(sAn, 1, kA); }
    BAR; MFMA_Q(0, aaA); BAR;

    RD_AA(aaA, (wn+2)&3, sA);
    if (stA){ stageA(sAn, 2, kA); stageA(sAn, 3, kA); }
    BAR; MFMA_Q(1, aaB); BAR;

    RD_AA(aaB, (wn+3)&3, sA);
    if (stB){ stageB(sB, 0, kB); stageB(sB, 1, kB); }
    BAR; MFMA_Q(2, aaA); BAR;

    if (stB){
      stageB(sB, 2, kB); stageB(sB, 3, kB);
      asm volatile("s_waitcnt vmcnt(4)" ::: "memory");
    } else {
      asm volatile("s_waitcnt vmcnt(0)" ::: "memory");
    }
    if (stA) RD_AA(aaA, wn, sAn);
    BAR; MFMA_Q(3, aaB); BAR;
  }
#undef RD_AA
#undef MFMA_Q
#undef BAR

  #pragma unroll
  for (int Pq=0; Pq<4; ++Pq){
    const int qd = (Pq+wn)&3;
    #pragma unroll
    for (int i2=0;i2<2;++i2){
      #pragma unroll
      for (int nf=0; nf<4; ++nf){
        #pragma unroll
        for (int r2=0; r2<4; ++r2){
          int row = wm*128 + qd*32 + i2*16 + (l>>4)*4 + r2;
          int col = wn*64 + nf*16 + (l&15);
          P[row*256 + col] = acc[2*Pq+i2][nf][r2];
        }
      }
    }
  }
}

// =====================================================================
// Gram reduce: per-128^2-quadrant, sum 3 fp32 partials -> bf16 + mirror.
// =====================================================================
__global__ __launch_bounds__(256) void k_gramred256(const float* __restrict__ Gp, bf16* __restrict__ Gram){
  const int t10o = blockIdx.x, b = blockIdx.y, q = blockIdx.z;
  const int qr = q>>1, qc = q&1;
  int td = t10o, i = 0;
  while (td >= 4 - i){ td -= 4 - i; ++i; }
  const int j = i + td;
  const float* P0 = Gp + ((size_t)(b*10 + t10o))*65536 + qr*128*256 + qc*128;
  const float* P1 = P0 + (size_t)80*65536;
  const float* P2 = P1 + (size_t)80*65536;
  bf16* C = Gram + (size_t)b*1048576;
  const int bm = i*256 + qr*128, bn = j*256 + qc*128;
  const bool domirror = !(i==j && qr==qc);
  __shared__ float sT[128][129];
  const int t = threadIdx.x;
  const int rr = t>>4, cc = (t&15)*8;
  #pragma unroll
  for (int ch=0; ch<8; ++ch){
    const int row = ch*16 + rr;
    const int idx = row*256 + cc;
    float4 a0 = *(const float4*)(P0+idx), a1 = *(const float4*)(P0+idx+4);
    float4 b0 = *(const float4*)(P1+idx), b1 = *(const float4*)(P1+idx+4);
    float4 c0 = *(const float4*)(P2+idx), c1 = *(const float4*)(P2+idx+4);
    float s[8] = {a0.x+b0.x+c0.x, a0.y+b0.y+c0.y, a0.z+b0.z+c0.z, a0.w+b0.w+c0.w,
                  a1.x+b1.x+c1.x, a1.y+b1.y+c1.y, a1.z+b1.z+c1.z, a1.w+b1.w+c1.w};
    union{ bf16 h[8]; uint4 u; } p;
    #pragma unroll
    for (int k=0;k<8;++k) p.h[k] = (bf16)s[k];
    *(uint4*)(C + (size_t)(bm+row)*1024 + bn + cc) = p.u;
    if (domirror){
      #pragma unroll
      for (int k=0;k<8;++k) sT[row][cc+k] = s[k];
    }
  }
  if (!domirror) return;
  __syncthreads();
  #pragma unroll
  for (int ch=0; ch<8; ++ch){
    const int c = ch*16 + rr;
    union{ bf16 h[8]; uint4 u; } p;
    #pragma unroll
    for (int k=0;k<8;++k) p.h[k] = (bf16)sT[cc+k][c];
    *(uint4*)(C + (size_t)(bn+c)*1024 + bm + cc) = p.u;
  }
}

// ---------- fused S = scale * T2_g @ Wv_g^T + row softmax -> Aatt[bg][64][64] ----------
__global__ __launch_bounds__(256) void k_sgemm64(const bf16* __restrict__ T2, const bf16* __restrict__ WqkvT,
                                                 bf16* __restrict__ Aatt){
  const int bg = blockIdx.x, b = bg>>4, g = bg&15;
  const bf16* Arows = T2 + (size_t)b*1048576 + (size_t)(g*64)*1024;
  const bf16* Brows = WqkvT + (size_t)(2048 + g*64)*1024;
  __shared__ __align__(16) bf16 sA[64*64];
  __shared__ __align__(16) bf16 sB[64*64];
  const int t = threadIdx.x, w = t>>6, l = t&63;
  const int srow = l>>3, scol = ((l&7)^(l>>3))*8;
  f32x4 acc[4] = {};
  for (int kt=0; kt<16; ++kt){
    const int k0 = kt*64;
    gload_lds16(Arows + (size_t)(w*8+srow)*1024 + k0 + scol,      sA + (w*8)*64);
    gload_lds16(Arows + (size_t)(32+w*8+srow)*1024 + k0 + scol,   sA + (32+w*8)*64);
    gload_lds16(Brows + (size_t)(w*8+srow)*1024 + k0 + scol,      sB + (w*8)*64);
    gload_lds16(Brows + (size_t)(32+w*8+srow)*1024 + k0 + scol,   sB + (32+w*8)*64);
    __syncthreads();
    #pragma unroll
    for (int kk=0; kk<64; kk+=32){
      const int xr = ((kk + 8*(l>>4))*2) ^ ((l&7)<<4);
      bf16x8 af = *(const bf16x8*)((const char*)sA + (w*16+(l&15))*128 + xr);
      #pragma unroll
      for (int nf=0; nf<4; ++nf){
        bf16x8 bfv = *(const bf16x8*)((const char*)sB + (nf*16+(l&15))*128 + xr);
        acc[nf] = __builtin_amdgcn_mfma_f32_16x16x32_bf16(af, bfv, acc[nf], 0,0,0);
      }
    }
    __syncthreads();
  }
  #pragma unroll
  for (int reg=0; reg<4; ++reg){
    float m = -3.4e38f;
    #pragma unroll
    for (int nf=0; nf<4; ++nf) m = fmaxf(m, acc[nf][reg]);
    m = fmaxf(m, __shfl_xor(m,1)); m = fmaxf(m, __shfl_xor(m,2));
    m = fmaxf(m, __shfl_xor(m,4)); m = fmaxf(m, __shfl_xor(m,8));
    float e[4]; float s = 0.f;
    #pragma unroll
    for (int nf=0; nf<4; ++nf){ e[nf] = __expf((acc[nf][reg]-m)*0.125f); s += e[nf]; }
    s += __shfl_xor(s,1); s += __shfl_xor(s,2); s += __shfl_xor(s,4); s += __shfl_xor(s,8);
    const float inv = 1.0f/s;
    const int row = w*16 + (l>>4)*4 + reg;
    #pragma unroll
    for (int nf=0; nf<4; ++nf)
      Aatt[(size_t)bg*4096 + row*64 + nf*16 + (l&15)] = (bf16)(e[nf]*inv);
  }
}

// ---------- U[c][g*64+d] = sum_e Wq[c][g*64+e] * Aatt_bg[d][e] ----------
__global__ __launch_bounds__(256) void k_applyW(const bf16* __restrict__ Wqkvb, const bf16* __restrict__ Aatt,
                                                bf16* __restrict__ U){
  const int bg = blockIdx.y, b = bg>>4, g = bg&15;
  const int m0 = blockIdx.x*128;
  __shared__ __align__(16) bf16 Pl[64][72];
  const int t = threadIdx.x, w = t>>6, l = t&63;
  for (int idx=t; idx<1024; idx+=256){
    int r2 = idx>>4, c4 = (idx&15)*4;
    *(uint2*)&Pl[r2][c4] = *(const uint2*)&Aatt[(size_t)bg*4096 + r2*64 + c4];
  }
  __syncthreads();
  f32x4 acc[2][4] = {};
  const bf16* Ab = Wqkvb + (size_t)(m0 + w*32)*3072 + g*64;
  #pragma unroll
  for (int kk=0; kk<64; kk+=32){
    bf16x8 af[2], pf[4];
    #pragma unroll
    for (int mf=0;mf<2;++mf)
      af[mf] = *(const bf16x8*)(Ab + (size_t)(mf*16 + (l&15))*3072 + kk + 8*(l>>4));
    #pragma unroll
    for (int nf=0;nf<4;++nf)
      pf[nf] = *(const bf16x8*)&Pl[nf*16 + (l&15)][kk + 8*(l>>4)];
    #pragma unroll
    for (int mf=0;mf<2;++mf)
      #pragma unroll
      for (int nf=0;nf<4;++nf)
        acc[mf][nf] = __builtin_amdgcn_mfma_f32_16x16x32_bf16(af[mf], pf[nf], acc[mf][nf], 0,0,0);
  }
  #pragma unroll
  for (int mf=0;mf<2;++mf)
    #pragma unroll
    for (int nf=0;nf<4;++nf)
      #pragma unroll
      for (int r=0;r<4;++r){
        int rowc = m0 + w*32 + mf*16 + (l>>4)*4 + r;
        int col = g*64 + nf*16 + (l&15);
        U[(size_t)b*1048576 + (size_t)rowc*1024 + col] = (bf16)acc[mf][nf][r];
      }
}

// ---------- LayerNorm: wave per row of 1024 ----------
__global__ __launch_bounds__(256) void k_ln(const bf16* __restrict__ h, const float* __restrict__ gamma,
                                            const float* __restrict__ beta, float* __restrict__ y){
  const int w = threadIdx.x>>6, l = threadIdx.x&63;
  const size_t row = (size_t)blockIdx.x*4 + w;
  const bf16* hr = h + row*1024 + l*16;
  uint4 p0 = *(const uint4*)hr;
  uint4 p1 = *(const uint4*)(hr+8);
  float v[16];
  const uint32_t* pw = (const uint32_t*)&p0;
  #pragma unroll
  for (int i=0;i<4;++i){ v[2*i] = bits2f(pw[i]<<16); v[2*i+1] = bits2f(pw[i]&0xffff0000u); }
  const uint32_t* pw1 = (const uint32_t*)&p1;
  #pragma unroll
  for (int i=0;i<4;++i){ v[8+2*i] = bits2f(pw1[i]<<16); v[8+2*i+1] = bits2f(pw1[i]&0xffff0000u); }
  float s=0.f, s2=0.f;
  #pragma unroll
  for (int i=0;i<16;++i){ s+=v[i]; s2+=v[i]*v[i]; }
  #pragma unroll
  for (int off=1; off<64; off<<=1){ s += __shfl_xor(s,off); s2 += __shfl_xor(s2,off); }
  float mu = s*(1.0f/1024.0f);
  float var = s2*(1.0f/1024.0f) - mu*mu;
  float rinv = rsqrtf(var + 1e-5f);
  const float* gp = gamma + l*16; const float* bp = beta + l*16;
  float o[16];
  #pragma unroll
  for (int i=0;i<16;++i) o[i] = gp[i]*(v[i]-mu)*rinv + bp[i];
  float* yr = y + row*1024 + l*16;
  #pragma unroll
  for (int i=0;i<4;++i) ((float4*)yr)[i] = *(float4*)&o[4*i];
}

extern "C" void kernel_launch(void* const* d_in, const int* in_sizes, int n_in,
                              void* d_out, int out_size, void* d_ws, size_t ws_size,
                              hipStream_t stream){
  const float* x     = (const float*)d_in[0];
  const float* Wqkv  = (const float*)d_in[1];
  const float* Wproj = (const float*)d_in[2];
  const float* bproj = (const float*)d_in[3];
  const float* gamma = (const float*)d_in[4];
  const float* beta  = (const float*)d_in[5];
  float* y = (float*)d_out;

  char* ws = (char*)d_ws;
  size_t off = 0;
  auto alloc = [&](size_t bytes)->void*{ void* p = ws + off; off += (bytes + 255) & ~(size_t)255; return p; };
  bf16*  xb     = (bf16*) alloc((size_t)32768*1024*2);   // 67.1 MB
  bf16*  xT     = (bf16*) alloc((size_t)8*1024*4096*2);  // 67.1 MB (reused as h)
  bf16*  Wqkvb  = (bf16*) alloc((size_t)1024*3072*2);
  bf16*  WqkvT  = (bf16*) alloc((size_t)3072*1024*2);
  bf16*  WprojT = (bf16*) alloc((size_t)1024*1024*2);
  bf16*  Gram   = (bf16*) alloc((size_t)8*1024*1024*2);  // 16.8 MB
  bf16*  T2     = (bf16*) alloc((size_t)8*1024*1024*2);
  bf16*  Aatt   = (bf16*) alloc((size_t)128*64*64*2);
  bf16*  U      = (bf16*) alloc((size_t)8*1024*1024*2);
  bf16*  WeffT  = (bf16*) alloc((size_t)8*1024*1024*2);
  float* Gp     = (float*)alloc((size_t)3*80*65536*4);   // 62.9 MB fp32 partials
  bf16*  h      = xT;   // xT dead after Gram

  const size_t MB1 = 1048576;
  const size_t MB4 = (size_t)4096*1024;

  k_castT<<<dim3(16,64,8),256,0,stream>>>(x, xb, xT);
  k_cast<<<1536,256,0,stream>>>(Wqkv, Wqkvb, 3145728);
  k_transpose<<<dim3(96,32),256,0,stream>>>(Wqkv, WqkvT, 1024, 3072);
  k_transpose<<<dim3(32,32),256,0,stream>>>(Wproj, WprojT, 1024, 1024);
  // Gram_b = xT_b @ xT_b^T (256^2 upper tiles, gemm256 pipeline, split-K 3)
  k_gram256<<<dim3(10,8,3),512,0,stream>>>(xT, Gp);
  k_gramred256<<<dim3(10,8,4),256,0,stream>>>(Gp, Gram);
  // T2_b = Wk^T @ Gram_b  [1024x1024], K=1024  (Gram symmetric)
  k_gemm128<0><<<dim3(8,8,8),256,0,stream>>>(WqkvT + (size_t)1024*1024, Gram, T2, 1024, 1024, 1024, 1024,
                                             0, MB1, MB1, nullptr, nullptr, 0);
  // S + softmax -> Aatt (fused)
  k_sgemm64<<<128,256,0,stream>>>(T2, WqkvT, Aatt);
  // U_b[:, g-block] = Wq_g @ Aatt_bg^T
  k_applyW<<<dim3(8,128),256,0,stream>>>(Wqkvb, Aatt, U);
  // WeffT_b = WprojT @ U_b^T  [1024x1024], K=1024
  k_gemm128<0><<<dim3(8,8,8),256,0,stream>>>(WprojT, U, WeffT, 1024, 1024, 1024, 1024,
                                             0, MB1, MB1, nullptr, nullptr, 0);
  // h_b = xb_b @ WeffT_b^T + bproj + xb_b   [4096x1024] per batch (grid MUST be (4,16,8))
  k_gemm256<<<dim3(4,16,8),512,0,stream>>>(xb, WeffT, h, 1024, 1024, bproj, xb,
                                           MB4, MB1, MB4, MB4);
  k_ln<<<8192,256,0,stream>>>(h, gamma, beta, y);
}